// Round 10
// baseline (199.338 us; speedup 1.0000x reference)
//
#include <hip/hip_runtime.h>
#include <math.h>

// Problem constants
#define BATCH 64
#define NPTS  2048
// ws float offsets
#define OFF_M    0       // [64][61] M[b][c*6+a], Sdw at [b][60]
#define OFF_T2   4096    // [64][18]  T2[m][a*3+j]
#define OFF_GP2  5248    // [128] S[64], Q[64] (atomic, zeroed by k_wa)
#define OFF_V    8192    // TRANSPOSED: Vt[v][ma] = [128][384]
#define OFF_WF1T 57344   // Wf1 transposed: [256 e][128 v]
#define OFF_C2   114688  // [64][64]  center2[b][m] (written by k_mid)
#define OFF_U2   118784  // [64][384] U2[b][ma] (written by k_mid)
#define OFF_MOM  143360  // [64][240] per-batch moments: A1[6],A2[18],B1[21],B2[63],B3[126]

// ---------------------------------------------------------------------------
// k_wa: blocks 0..23    fold-V as tiled GEMM (a, v-quarter)
//       blocks 24..41   fold-T2 (one (a,j) pair per block)
//       blocks 42..105  stage-A per-batch moments (M, dw-weighted)
//       block 106       zero GP2
//       blocks 107..114 transpose Wf1 -> Wf1t
//       blocks 115..178 bn3 moments group0: B3
//       blocks 179..242 bn3 moments group1: A1,A2,B1,B2
__global__ __launch_bounds__(256) void k_wa(const float* __restrict__ x,
                                            const float* __restrict__ Wm0,
                                            const float* __restrict__ Wdc,
                                            const float* __restrict__ Wf1,
                                            float* __restrict__ ws) {
    __shared__ __attribute__((aligned(16))) float L[61 * 257];
    int blk = blockIdx.x, t = threadIdx.x;
    if (blk < 24) {
        float* wml = L;            // [64][33]
        float* pl  = L + 2112;     // [32][36]
        int a = blk >> 2, vq = blk & 3;
        int m = t & 63, vg = t >> 6;
        float acc[8];
#pragma unroll
        for (int i = 0; i < 8; ++i) acc[i] = 0.f;
        for (int e0 = 0; e0 < 256; e0 += 32) {
            for (int g = t; g < 2048; g += 256)
                wml[(g >> 5) * 33 + (g & 31)] = Wm0[(g >> 5) * 256 + e0 + (g & 31)];
            for (int g = t; g < 1024; g += 256)
                pl[(g >> 5) * 36 + (g & 31)] =
                    Wdc[((e0 + (g >> 5)) * 6 + a) * 131 + 3 + vq * 32 + (g & 31)];
            __syncthreads();
#pragma unroll
            for (int e = 0; e < 32; ++e) {
                float wv = wml[m * 33 + e];
                const float4* p4 = (const float4*)(pl + e * 36 + vg * 8);
                float4 pa = p4[0], pb = p4[1];
                acc[0] = fmaf(wv, pa.x, acc[0]); acc[1] = fmaf(wv, pa.y, acc[1]);
                acc[2] = fmaf(wv, pa.z, acc[2]); acc[3] = fmaf(wv, pa.w, acc[3]);
                acc[4] = fmaf(wv, pb.x, acc[4]); acc[5] = fmaf(wv, pb.y, acc[5]);
                acc[6] = fmaf(wv, pb.z, acc[6]); acc[7] = fmaf(wv, pb.w, acc[7]);
            }
            __syncthreads();
        }
#pragma unroll
        for (int vv = 0; vv < 8; ++vv)
            ws[OFF_V + (vq * 32 + vg * 8 + vv) * 384 + m * 6 + a] = acc[vv];
    } else if (blk < 42) {
        float* col = L;
        float* red = L + 256;
        int p = blk - 24, a = p / 3, j = p % 3;
        col[t] = Wdc[(t * 6 + a) * 131 + j];
        __syncthreads();
        int m = t >> 2, q = t & 3;
        const float* wm = Wm0 + m * 256 + q * 64;
        const float* cl = col + q * 64;
        float s = 0.f;
#pragma unroll 8
        for (int i = 0; i < 64; ++i) s = fmaf(wm[i], cl[i], s);
        red[t] = s;
        __syncthreads();
        if (t < 64) {
            float v = (red[t * 4] + red[t * 4 + 1]) + (red[t * 4 + 2] + red[t * 4 + 3]);
            ws[OFF_T2 + t * 18 + a * 3 + j] = v;
        }
    } else if (blk < 106) {
        int b = blk - 42;
        float* red = L;                        // [61][257]
        float acc[61];
#pragma unroll
        for (int i = 0; i < 61; ++i) acc[i] = 0.f;
#pragma unroll 2
        for (int k = 0; k < 8; ++k) {
            int n = t + 256 * k;
            const float* xp = x + (size_t)(b * NPTS + n) * 10;
            float xv[10];
#pragma unroll
            for (int j = 0; j < 5; ++j) {
                float2 v = *(const float2*)(xp + 2 * j);
                xv[2 * j] = v.x; xv[2 * j + 1] = v.y;
            }
            float x0 = xv[0], x1 = xv[1], x2 = xv[2];
            float rn = x0 * x0 + x1 * x1 + x2 * x2;
            float norm = sqrtf(rn);
            float inv = 1.f / (norm + 1e-8f);
            float c2[6];
            c2[0] = fmaxf(x2, 0.f) * inv; c2[1] = fmaxf(-x2, 0.f) * inv;
            c2[2] = fmaxf(x1, 0.f) * inv; c2[3] = fmaxf(-x1, 0.f) * inv;
            c2[4] = fmaxf(x0, 0.f) * inv; c2[5] = fmaxf(-x0, 0.f) * inv;
#pragma unroll
            for (int a = 0; a < 6; ++a) c2[a] *= c2[a];
            float dw = 1.f - (rn - 1.f) * (1.f / 3.f);
            if (dw < 0.f) dw = 0.f;
            if (norm <= 0.f) dw = 0.f;
            float cw[6];
#pragma unroll
            for (int a = 0; a < 6; ++a) cw[a] = c2[a] * dw;
#pragma unroll
            for (int c = 0; c < 10; ++c) {
                float dv = (c < 7) ? xv[3 + c] : xv[c - 7];
#pragma unroll
                for (int a = 0; a < 6; ++a)
                    acc[c * 6 + a] = fmaf(dv, cw[a], acc[c * 6 + a]);
            }
            acc[60] += dw;
        }
#pragma unroll
        for (int i = 0; i < 61; ++i) red[i * 257 + t] = acc[i];
        __syncthreads();
        if (t < 61) {
            float s = 0.f;
#pragma unroll 8
            for (int j = 0; j < 256; ++j) s += red[t * 257 + j];
            ws[OFF_M + b * 61 + t] = s;
        }
    } else if (blk == 106) {
        if (t < 128) ws[OFF_GP2 + t] = 0.f;
    } else if (blk < 115) {
        float* slab = L;                       // [16][257]
        int w = blk - 107, v0 = w * 16;
        for (int g = t; g < 4096; g += 256)
            slab[(g >> 8) * 257 + (g & 255)] = Wf1[(v0 + (g >> 8)) * 256 + (g & 255)];
        __syncthreads();
        for (int g = t; g < 4096; g += 256) {
            int e = g >> 4, vl = g & 15;
            ws[OFF_WF1T + e * 128 + v0 + vl] = slab[vl * 257 + e];
        }
    } else if (blk < 179) {
        int b = blk - 115;
        float* red = L;
        float acc[126];
#pragma unroll
        for (int i = 0; i < 126; ++i) acc[i] = 0.f;
        for (int k = 0; k < 8; ++k) {
            int n = t + 256 * k;
            const float* xp = x + (size_t)(b * NPTS + n) * 10;
            float x0 = xp[0], x1 = xp[1], x2 = xp[2];
            float rn = x0 * x0 + x1 * x1 + x2 * x2;
            float inv = 1.f / (sqrtf(rn) + 1e-8f);
            float c[6];
            c[0] = fmaxf(x2, 0.f) * inv; c[1] = fmaxf(-x2, 0.f) * inv;
            c[2] = fmaxf(x1, 0.f) * inv; c[3] = fmaxf(-x1, 0.f) * inv;
            c[4] = fmaxf(x0, 0.f) * inv; c[5] = fmaxf(-x0, 0.f) * inv;
#pragma unroll
            for (int a = 0; a < 6; ++a) c[a] *= c[a];
            float xx[6] = {x0 * x0, x0 * x1, x0 * x2, x1 * x1, x1 * x2, x2 * x2};
#pragma unroll
            for (int a = 0; a < 6; ++a)
#pragma unroll
                for (int a2 = a; a2 < 6; ++a2) {
                    int p = a * 6 - (a * (a - 1)) / 2 + (a2 - a);
                    float cc = c[a] * c[a2];
#pragma unroll
                    for (int q = 0; q < 6; ++q)
                        acc[p * 6 + q] = fmaf(cc, xx[q], acc[p * 6 + q]);
                }
        }
#pragma unroll
        for (int i = 0; i < 61; ++i) red[i * 257 + t] = acc[i];
        __syncthreads();
        if (t < 61) {
            float s = 0.f;
#pragma unroll 8
            for (int j = 0; j < 256; ++j) s += red[t * 257 + j];
            ws[OFF_MOM + b * 240 + 108 + t] = s;
        }
        __syncthreads();
#pragma unroll
        for (int i = 0; i < 61; ++i) red[i * 257 + t] = acc[61 + i];
        __syncthreads();
        if (t < 61) {
            float s = 0.f;
#pragma unroll 8
            for (int j = 0; j < 256; ++j) s += red[t * 257 + j];
            ws[OFF_MOM + b * 240 + 108 + 61 + t] = s;
        }
        __syncthreads();
#pragma unroll
        for (int i = 0; i < 4; ++i) red[i * 257 + t] = acc[122 + i];
        __syncthreads();
        if (t < 4) {
            float s = 0.f;
#pragma unroll 8
            for (int j = 0; j < 256; ++j) s += red[t * 257 + j];
            ws[OFF_MOM + b * 240 + 108 + 122 + t] = s;
        }
    } else {
        int b = blk - 179;
        float* red = L;
        float acc[108];
#pragma unroll
        for (int i = 0; i < 108; ++i) acc[i] = 0.f;
        for (int k = 0; k < 8; ++k) {
            int n = t + 256 * k;
            const float* xp = x + (size_t)(b * NPTS + n) * 10;
            float x0 = xp[0], x1 = xp[1], x2 = xp[2];
            float rn = x0 * x0 + x1 * x1 + x2 * x2;
            float inv = 1.f / (sqrtf(rn) + 1e-8f);
            float c[6];
            c[0] = fmaxf(x2, 0.f) * inv; c[1] = fmaxf(-x2, 0.f) * inv;
            c[2] = fmaxf(x1, 0.f) * inv; c[3] = fmaxf(-x1, 0.f) * inv;
            c[4] = fmaxf(x0, 0.f) * inv; c[5] = fmaxf(-x0, 0.f) * inv;
#pragma unroll
            for (int a = 0; a < 6; ++a) c[a] *= c[a];
#pragma unroll
            for (int a = 0; a < 6; ++a) {
                acc[a] += c[a];
                acc[6 + a * 3 + 0] = fmaf(c[a], x0, acc[6 + a * 3 + 0]);
                acc[6 + a * 3 + 1] = fmaf(c[a], x1, acc[6 + a * 3 + 1]);
                acc[6 + a * 3 + 2] = fmaf(c[a], x2, acc[6 + a * 3 + 2]);
            }
#pragma unroll
            for (int a = 0; a < 6; ++a)
#pragma unroll
                for (int a2 = a; a2 < 6; ++a2) {
                    int p = a * 6 - (a * (a - 1)) / 2 + (a2 - a);
                    float cc = c[a] * c[a2];
                    acc[24 + p] += cc;
                    acc[45 + p * 3 + 0] = fmaf(cc, x0, acc[45 + p * 3 + 0]);
                    acc[45 + p * 3 + 1] = fmaf(cc, x1, acc[45 + p * 3 + 1]);
                    acc[45 + p * 3 + 2] = fmaf(cc, x2, acc[45 + p * 3 + 2]);
                }
        }
#pragma unroll
        for (int i = 0; i < 61; ++i) red[i * 257 + t] = acc[i];
        __syncthreads();
        if (t < 61) {
            float s = 0.f;
#pragma unroll 8
            for (int j = 0; j < 256; ++j) s += red[t * 257 + j];
            ws[OFF_MOM + b * 240 + t] = s;
        }
        __syncthreads();
#pragma unroll
        for (int i = 0; i < 47; ++i) red[i * 257 + t] = acc[61 + i];
        __syncthreads();
        if (t < 47) {
            float s = 0.f;
#pragma unroll 8
            for (int j = 0; j < 256; ++j) s += red[t * 257 + j];
            ws[OFF_MOM + b * 240 + 61 + t] = s;
        }
    }
}

// ---------------------------------------------------------------------------
// k_mid: k_d2 + k_z merged. 64 blocks x 512 threads (one per batch). Each
// block redundantly computes h1/bn1 (same FP chains as k_d2), then d2+bn2 in
// 8 chunks of 32 e (same per-e FP order), keeping only its own batch's d2'
// row; then z, U2, C2, closed-form bn3 S/Q + point-0 correction -> GP2.
// All cold staging (M, Wdir, Wdir2, Wcm, mom) overlapped in one kernel.
__global__ __launch_bounds__(512) void k_mid(const float* __restrict__ x,
                                             const float* __restrict__ Wdir,
                                             const float* __restrict__ g1,
                                             const float* __restrict__ b1,
                                             const float* __restrict__ Wdir2,
                                             const float* __restrict__ g2,
                                             const float* __restrict__ b2,
                                             const float* __restrict__ bf1,
                                             const float* __restrict__ Wcm,
                                             const float* __restrict__ bcm,
                                             float* __restrict__ ws) {
    __shared__ __attribute__((aligned(16))) float L[14900];   // 59.6 KB union
    float* Ml    = L;            // [64][61]  (phase A-B)
    float* Wd    = L + 3904;     // [64][61]  (phase A-B)
    float* w2c   = L;            // [32][65]  (phase D, Ml dead)
    float* d2c   = L + 3904;     // [64][33]  (phase D, Wd dead)
    float* h1    = L + 7808;     // [64][65]  (phase B-D)
    float* wcm   = L;            // [64][133] (phase F, spans 0..8512; all dead)
    float* d2row = L + 11968;    // [256]
    float* T2l   = L + 12224;    // [1152]
    float* mom   = L + 13376;    // [240]
    float* x0l   = L + 13616;    // [4]
    float* zl    = L + 13620;    // [128]
    float* zp    = L + 13748;    // [512]
    float* U2l   = L + 14260;    // [384]
    float* C2l   = L + 14644;    // [64]
    float* sc    = L + 14708;    // [64]
    float* of    = L + 14772;    // [64]
    float* scl   = L + 14836;    // [32]
    float* ofl   = L + 14868;    // [32]
    int b = blockIdx.x, t = threadIdx.x;

    // ---- A: stage everything cold, all at once (latency overlap)
    for (int g = t; g < 3904; g += 512) Ml[g] = ws[OFF_M + g];
    for (int g = t; g < 3840; g += 512) Wd[(g / 60) * 61 + g % 60] = Wdir[g];
    for (int g = t; g < 1152; g += 512) T2l[g] = ws[OFF_T2 + g];
    if (t < 234) mom[t] = ws[OFF_MOM + b * 240 + t];
    if (t < 3) x0l[t] = x[(size_t)b * NPTS * 10 + t];
    __syncthreads();

    // ---- B: h1 (same per-(b,m) fma chains as k_d2)
    int m = t & 63;
    float Wr[60];
#pragma unroll
    for (int r = 0; r < 60; ++r) Wr[r] = Wd[m * 61 + r];
#pragma unroll
    for (int k = 0; k < 8; ++k) {
        int idx = t + 512 * k;
        int bb = idx >> 6;
        const float* Mb = Ml + bb * 61;
        float s = 0.f;
#pragma unroll
        for (int a = 0; a < 6; ++a)
#pragma unroll
            for (int c = 0; c < 10; ++c)
                s = fmaf(Wr[a * 10 + c], Mb[c * 6 + a], s);
        h1[bb * 65 + m] = s / Mb[60];
    }
    __syncthreads();

    // ---- C: bn1 + relu (same FP order)
    if (t < 64) {
        float s = 0.f, q = 0.f;
#pragma unroll 8
        for (int bb = 0; bb < 64; ++bb) { float v = h1[bb * 65 + t]; s += v; q = fmaf(v, v, q); }
        float mean = s * (1.f / 64.f);
        float var = q * (1.f / 64.f) - mean * mean;
        float scale = g1[t] * rsqrtf(var + 1e-5f);
        sc[t] = scale; of[t] = b1[t] - mean * scale;
    }
    __syncthreads();
#pragma unroll
    for (int k = 0; k < 8; ++k) {
        int idx = t + 512 * k;
        int bb = idx >> 6;
        h1[bb * 65 + m] = fmaxf(fmaf(h1[bb * 65 + m], sc[m], of[m]), 0.f);
    }
    __syncthreads();

    // ---- D: d2 + bn2 in 8 chunks of 32 e; keep only own batch's d2' row
    for (int c8 = 0; c8 < 8; ++c8) {
        int e_base = c8 * 32;
        for (int g = t; g < 2048; g += 512)
            w2c[(g >> 6) * 65 + (g & 63)] = Wdir2[(e_base + (g >> 6)) * 64 + (g & 63)];
        __syncthreads();
#pragma unroll
        for (int i = 0; i < 4; ++i) {
            int idx = t + 512 * i;
            int bb = idx >> 5, el = idx & 31;
            const float* h = h1 + bb * 65;
            const float* w = w2c + el * 65;
            float s = 0.f;
#pragma unroll
            for (int mm = 0; mm < 64; ++mm) s = fmaf(h[mm], w[mm], s);
            d2c[bb * 33 + el] = s;
        }
        __syncthreads();
        if (t < 32) {
            float s = 0.f, q = 0.f;
#pragma unroll 8
            for (int bb = 0; bb < 64; ++bb) { float v = d2c[bb * 33 + t]; s += v; q = fmaf(v, v, q); }
            float mean = s * (1.f / 64.f);
            float var = q * (1.f / 64.f) - mean * mean;
            int E = e_base + t;
            float scale = g2[E] * rsqrtf(var + 1e-5f);
            float off = b2[E] - mean * scale;
            d2row[E] = fmaxf(fmaf(d2c[b * 33 + t], scale, off), 0.f);
        }
        __syncthreads();
    }

    // ---- E: Wcm stage (regions dead) + z partials (same 4x64 structure)
    for (int g = t; g < 8384; g += 512) wcm[(g / 131) * 133 + g % 131] = Wcm[g];
    {
        int q = t >> 7, v = t & 127;
        const float* Wt = ws + OFF_WF1T + (q * 64) * 128 + v;
        const float* d = d2row + q * 64;
        float s = 0.f;
#pragma unroll 8
        for (int e = 0; e < 64; ++e) s = fmaf(d[e], Wt[e * 128], s);
        zp[q * 128 + v] = s;
    }
    __syncthreads();
    if (t < 128)
        zl[t] = bf1[t] + ((zp[t] + zp[128 + t]) + (zp[256 + t] + zp[384 + t]));
    __syncthreads();

    // ---- F: U2 + C2 (verbatim from k_z)
    if (t < 384) {
        const float* Vt = ws + OFF_V;
        float s0 = 0.f;
#pragma unroll 8
        for (int v = 0; v < 128; ++v) s0 = fmaf(zl[v], Vt[v * 384 + t], s0);
        U2l[t] = s0;
        ws[OFF_U2 + b * 384 + t] = s0;
    } else if (t < 448) {
        int mm = t - 384;
        const float* w = wcm + mm * 133;
        float s = bcm[mm];
#pragma unroll 4
        for (int i = 0; i < 128; ++i) s = fmaf(zl[i], w[i], s);
        s = fmaf(x0l[0], w[128], s);
        s = fmaf(x0l[1], w[129], s);
        s = fmaf(x0l[2], w[130], s);
        ws[OFF_C2 + b * 64 + mm] = s;
        C2l[mm] = s;
    }
    __syncthreads();

    // ---- G: closed-form S/Q + point-0 correction (verbatim from k_z)
    if (t < 64) {
        int mm = t;
        float T[18], U[6];
#pragma unroll
        for (int r = 0; r < 18; ++r) T[r] = T2l[mm * 18 + r];
#pragma unroll
        for (int a = 0; a < 6; ++a) U[a] = U2l[mm * 6 + a];
        float S = 0.f;
#pragma unroll
        for (int a = 0; a < 6; ++a) {
            S = fmaf(mom[6 + a * 3 + 0], T[a * 3 + 0], S);
            S = fmaf(mom[6 + a * 3 + 1], T[a * 3 + 1], S);
            S = fmaf(mom[6 + a * 3 + 2], T[a * 3 + 2], S);
            S = fmaf(mom[a], U[a], S);
        }
        float qd = 0.f, qo = 0.f;
#pragma unroll
        for (int a = 0; a < 6; ++a)
#pragma unroll
            for (int a2 = a; a2 < 6; ++a2) {
                int p = a * 6 - (a * (a - 1)) / 2 + (a2 - a);
                const float* b3 = mom + 108 + p * 6;
                const float* b2m = mom + 45 + p * 3;
                float b1v = mom[24 + p];
                float Ta0 = T[a * 3], Ta1 = T[a * 3 + 1], Ta2 = T[a * 3 + 2];
                float Tb0 = T[a2 * 3], Tb1 = T[a2 * 3 + 1], Tb2 = T[a2 * 3 + 2];
                float w0 = b3[0] * Ta0 + b3[1] * Ta1 + b3[2] * Ta2;
                float w1 = b3[1] * Ta0 + b3[3] * Ta1 + b3[4] * Ta2;
                float w2 = b3[2] * Ta0 + b3[4] * Ta1 + b3[5] * Ta2;
                float term = w0 * Tb0 + w1 * Tb1 + w2 * Tb2;
                float d1 = b2m[0] * Ta0 + b2m[1] * Ta1 + b2m[2] * Ta2;
                float d2_ = b2m[0] * Tb0 + b2m[1] * Tb1 + b2m[2] * Tb2;
                term += U[a2] * d1 + U[a] * d2_ + U[a] * U[a2] * b1v;
                if (a == a2) qd += term; else qo += term;
            }
        float Q = qd + 2.f * qo;
        float xx0 = x0l[0], xx1 = x0l[1], xx2 = x0l[2];
        float rn = xx0 * xx0 + xx1 * xx1 + xx2 * xx2;
        float inv = 1.f / (sqrtf(rn) + 1e-8f);
        float c2[6];
        c2[0] = fmaxf(xx2, 0.f) * inv; c2[1] = fmaxf(-xx2, 0.f) * inv;
        c2[2] = fmaxf(xx1, 0.f) * inv; c2[3] = fmaxf(-xx1, 0.f) * inv;
        c2[4] = fmaxf(xx0, 0.f) * inv; c2[5] = fmaxf(-xx0, 0.f) * inv;
        float h0 = 0.f;
#pragma unroll
        for (int a = 0; a < 6; ++a) {
            float cc = c2[a] * c2[a];
            float ta = fmaf(xx0, T[a * 3], fmaf(xx1, T[a * 3 + 1], fmaf(xx2, T[a * 3 + 2], U[a])));
            h0 = fmaf(cc, ta, h0);
        }
        float C2v = C2l[mm];
        S += C2v - h0;
        Q += C2v * C2v - h0 * h0;
        atomicAdd(&ws[OFF_GP2 + mm], S);
        atomicAdd(&ws[OFF_GP2 + 64 + mm], Q);
    }
}

// ---------------------------------------------------------------------------
// k_e: epilogue; per-block bn3 scale/off from the single GP2 row.
__global__ __launch_bounds__(512) void k_e(const float* __restrict__ x,
                                           const float* __restrict__ g3,
                                           const float* __restrict__ b3,
                                           const float* __restrict__ Wf2,
                                           const float* __restrict__ bf2,
                                           const float* __restrict__ ws,
                                           float* __restrict__ out) {
    __shared__ __attribute__((aligned(16))) float L[6464];
    float* Wl24 = L;           // [64][24]
    float* Pl   = L + 1536;    // [64][12]
    float* C2l  = L + 2304;    // [64]
    float* yp   = L + 2368;    // [256][16]
    int blk = blockIdx.x, t = threadIdx.x;
    int b = blk >> 3;
    for (int g = t; g < 1152; g += 512) {
        int m = g / 18, r = g % 18, a = r / 3, j = r % 3;
        Wl24[m * 24 + a * 4 + j] = ws[OFF_T2 + g];
    }
    if (t < 384)
        Wl24[(t / 6) * 24 + (t % 6) * 4 + 3] = ws[OFF_U2 + b * 384 + t];
    if (t < 448) {
        int m = t / 7, k = t % 7;
        Pl[m * 12 + k] = Wf2[k * 64 + m];
    }
    if (t < 64) {
        float S = ws[OFF_GP2 + t];
        float Q = ws[OFF_GP2 + 64 + t];
        float mean = S * (1.f / 131072.f);
        float var = Q * (1.f / 131072.f) - mean * mean;
        float scale = g3[t] * rsqrtf(var + 1e-5f);
        Pl[t * 12 + 7] = scale;
        Pl[t * 12 + 8] = b3[t] - mean * scale;
    }
    if ((blk & 7) == 0 && t < 64) C2l[t] = ws[OFF_C2 + b * 64 + t];
    __syncthreads();

    int p_loc = t >> 1, mh = t & 1;
    int p = blk * 256 + p_loc;
    const float* xp = x + (size_t)p * 10;
    float x0 = xp[0], x1 = xp[1], x2 = xp[2];
    float rn = x0 * x0 + x1 * x1 + x2 * x2;
    float inv = 1.f / (sqrtf(rn) + 1e-8f);
    float c2[6];
    c2[0] = fmaxf(x2, 0.f) * inv; c2[1] = fmaxf(-x2, 0.f) * inv;
    c2[2] = fmaxf(x1, 0.f) * inv; c2[3] = fmaxf(-x1, 0.f) * inv;
    c2[4] = fmaxf(x0, 0.f) * inv; c2[5] = fmaxf(-x0, 0.f) * inv;
#pragma unroll
    for (int a = 0; a < 6; ++a) c2[a] *= c2[a];
    bool c0 = ((p & 2047) == 0);
    float y[7];
#pragma unroll
    for (int k = 0; k < 7; ++k) y[k] = mh ? 0.f : bf2[k];
    int m0 = mh * 32;
#pragma unroll 4
    for (int mm = 0; mm < 32; ++mm) {
        int m = m0 + mm;
        const float4* Wm = (const float4*)(Wl24 + m * 24);
        float h = 0.f;
#pragma unroll
        for (int a = 0; a < 6; ++a) {
            float4 wq = Wm[a];
            float ta = fmaf(x0, wq.x, fmaf(x1, wq.y, fmaf(x2, wq.z, wq.w)));
            h = fmaf(c2[a], ta, h);
        }
        if (c0) h = C2l[m];
        const float4* Pm = (const float4*)(Pl + m * 12);
        float4 p0 = Pm[0], p1 = Pm[1];
        float offv = Pl[m * 12 + 8];
        float r = fmaxf(fmaf(h, p1.w, offv), 0.f);
        y[0] = fmaf(r, p0.x, y[0]); y[1] = fmaf(r, p0.y, y[1]);
        y[2] = fmaf(r, p0.z, y[2]); y[3] = fmaf(r, p0.w, y[3]);
        y[4] = fmaf(r, p1.x, y[4]); y[5] = fmaf(r, p1.y, y[5]);
        y[6] = fmaf(r, p1.z, y[6]);
    }
#pragma unroll
    for (int k = 0; k < 7; ++k) yp[p_loc * 16 + mh * 8 + k] = y[k];
    __syncthreads();
    float* op = out + (size_t)blk * 1792;
    for (int g = t; g < 1792; g += 512) {
        int pp = g / 7, k = g % 7;
        float v = yp[pp * 16 + k] + yp[pp * 16 + 8 + k];
        op[g] = 1.f / (1.f + __expf(-v));
    }
}

// ---------------------------------------------------------------------------
extern "C" void kernel_launch(void* const* d_in, const int* in_sizes, int n_in,
                              void* d_out, int out_size, void* d_ws, size_t ws_size,
                              hipStream_t stream) {
    const float* x     = (const float*)d_in[0];
    // d_in[1]=Wc, d_in[2]=bc : dead code in reference
    const float* Wdir  = (const float*)d_in[3];
    const float* g1    = (const float*)d_in[4];
    const float* b1    = (const float*)d_in[5];
    const float* Wdir2 = (const float*)d_in[6];
    const float* g2    = (const float*)d_in[7];
    const float* b2    = (const float*)d_in[8];
    const float* Wf1   = (const float*)d_in[9];
    const float* bf1   = (const float*)d_in[10];
    const float* Wcm   = (const float*)d_in[11];
    const float* bcm   = (const float*)d_in[12];
    const float* Wdc   = (const float*)d_in[13];
    const float* Wm0   = (const float*)d_in[14];
    const float* g3    = (const float*)d_in[15];
    const float* b3    = (const float*)d_in[16];
    const float* Wf2   = (const float*)d_in[17];
    const float* bf2   = (const float*)d_in[18];
    float* ws  = (float*)d_ws;
    float* out = (float*)d_out;

    k_wa <<<243, 256, 0, stream>>>(x, Wm0, Wdc, Wf1, ws);
    k_mid<<<64,  512, 0, stream>>>(x, Wdir, g1, b1, Wdir2, g2, b2, bf1, Wcm, bcm, ws);
    k_e  <<<512, 512, 0, stream>>>(x, g3, b3, Wf2, bf2, ws, out);
}

// Round 11
// 159.073 us; speedup vs baseline: 1.2531x; 1.2531x over previous
//
#include <hip/hip_runtime.h>
#include <math.h>

// Problem constants
#define BATCH 64
#define NPTS  2048
// ws float offsets
#define OFF_M    0       // [64][61] M[b][c*6+a], Sdw at [b][60] (dead after k_d2)
#define OFF_T2   4096    // [64][18]  T2[m][a*3+j]
#define OFF_GP2  5248    // [128] S[64], Q[64] (atomic, zeroed by k_wa)
#define OFF_V    8192    // TRANSPOSED: Vt[v][ma] = [128][384]
#define OFF_WF1T 57344   // Wf1 transposed: [256 e][128 v]
#define OFF_D2P  90112   // [64][256] relu(bn2(d2))
#define OFF_C2   114688  // [64][64]  center2[b][m] (written by k_z)
#define OFF_U2   118784  // [64][384] U2[b][ma] (written by k_z)
#define OFF_MOM  143360  // [64][240] per-batch moments: A1[6],A2[18],B1[21],B2[63],B3[126]

// ---------------------------------------------------------------------------
// k_wa: blocks 0..23    fold-V as tiled GEMM (a, v-quarter)
//       blocks 24..41   fold-T2 (one (a,j) pair per block)
//       blocks 42..105  stage-A per-batch moments (M, dw-weighted)
//       block 106       zero GP2
//       blocks 107..114 transpose Wf1 -> Wf1t
//       blocks 115..178 bn3 moments group0: B3
//       blocks 179..242 bn3 moments group1: A1,A2,B1,B2
__global__ __launch_bounds__(256) void k_wa(const float* __restrict__ x,
                                            const float* __restrict__ Wm0,
                                            const float* __restrict__ Wdc,
                                            const float* __restrict__ Wf1,
                                            float* __restrict__ ws) {
    __shared__ __attribute__((aligned(16))) float L[61 * 257];
    int blk = blockIdx.x, t = threadIdx.x;
    if (blk < 24) {
        float* wml = L;            // [64][33]
        float* pl  = L + 2112;     // [32][36]
        int a = blk >> 2, vq = blk & 3;
        int m = t & 63, vg = t >> 6;
        float acc[8];
#pragma unroll
        for (int i = 0; i < 8; ++i) acc[i] = 0.f;
        for (int e0 = 0; e0 < 256; e0 += 32) {
            for (int g = t; g < 2048; g += 256)
                wml[(g >> 5) * 33 + (g & 31)] = Wm0[(g >> 5) * 256 + e0 + (g & 31)];
            for (int g = t; g < 1024; g += 256)
                pl[(g >> 5) * 36 + (g & 31)] =
                    Wdc[((e0 + (g >> 5)) * 6 + a) * 131 + 3 + vq * 32 + (g & 31)];
            __syncthreads();
#pragma unroll
            for (int e = 0; e < 32; ++e) {
                float wv = wml[m * 33 + e];
                const float4* p4 = (const float4*)(pl + e * 36 + vg * 8);
                float4 pa = p4[0], pb = p4[1];
                acc[0] = fmaf(wv, pa.x, acc[0]); acc[1] = fmaf(wv, pa.y, acc[1]);
                acc[2] = fmaf(wv, pa.z, acc[2]); acc[3] = fmaf(wv, pa.w, acc[3]);
                acc[4] = fmaf(wv, pb.x, acc[4]); acc[5] = fmaf(wv, pb.y, acc[5]);
                acc[6] = fmaf(wv, pb.z, acc[6]); acc[7] = fmaf(wv, pb.w, acc[7]);
            }
            __syncthreads();
        }
#pragma unroll
        for (int vv = 0; vv < 8; ++vv)
            ws[OFF_V + (vq * 32 + vg * 8 + vv) * 384 + m * 6 + a] = acc[vv];
    } else if (blk < 42) {
        float* col = L;
        float* red = L + 256;
        int p = blk - 24, a = p / 3, j = p % 3;
        col[t] = Wdc[(t * 6 + a) * 131 + j];
        __syncthreads();
        int m = t >> 2, q = t & 3;
        const float* wm = Wm0 + m * 256 + q * 64;
        const float* cl = col + q * 64;
        float s = 0.f;
#pragma unroll 8
        for (int i = 0; i < 64; ++i) s = fmaf(wm[i], cl[i], s);
        red[t] = s;
        __syncthreads();
        if (t < 64) {
            float v = (red[t * 4] + red[t * 4 + 1]) + (red[t * 4 + 2] + red[t * 4 + 3]);
            ws[OFF_T2 + t * 18 + a * 3 + j] = v;
        }
    } else if (blk < 106) {
        int b = blk - 42;
        float* red = L;                        // [61][257]
        float acc[61];
#pragma unroll
        for (int i = 0; i < 61; ++i) acc[i] = 0.f;
#pragma unroll 2
        for (int k = 0; k < 8; ++k) {
            int n = t + 256 * k;
            const float* xp = x + (size_t)(b * NPTS + n) * 10;
            float xv[10];
#pragma unroll
            for (int j = 0; j < 5; ++j) {
                float2 v = *(const float2*)(xp + 2 * j);
                xv[2 * j] = v.x; xv[2 * j + 1] = v.y;
            }
            float x0 = xv[0], x1 = xv[1], x2 = xv[2];
            float rn = x0 * x0 + x1 * x1 + x2 * x2;
            float norm = sqrtf(rn);
            float inv = 1.f / (norm + 1e-8f);
            float c2[6];
            c2[0] = fmaxf(x2, 0.f) * inv; c2[1] = fmaxf(-x2, 0.f) * inv;
            c2[2] = fmaxf(x1, 0.f) * inv; c2[3] = fmaxf(-x1, 0.f) * inv;
            c2[4] = fmaxf(x0, 0.f) * inv; c2[5] = fmaxf(-x0, 0.f) * inv;
#pragma unroll
            for (int a = 0; a < 6; ++a) c2[a] *= c2[a];
            float dw = 1.f - (rn - 1.f) * (1.f / 3.f);
            if (dw < 0.f) dw = 0.f;
            if (norm <= 0.f) dw = 0.f;
            float cw[6];
#pragma unroll
            for (int a = 0; a < 6; ++a) cw[a] = c2[a] * dw;
#pragma unroll
            for (int c = 0; c < 10; ++c) {
                float dv = (c < 7) ? xv[3 + c] : xv[c - 7];
#pragma unroll
                for (int a = 0; a < 6; ++a)
                    acc[c * 6 + a] = fmaf(dv, cw[a], acc[c * 6 + a]);
            }
            acc[60] += dw;
        }
#pragma unroll
        for (int i = 0; i < 61; ++i) red[i * 257 + t] = acc[i];
        __syncthreads();
        if (t < 61) {
            float s = 0.f;
#pragma unroll 8
            for (int j = 0; j < 256; ++j) s += red[t * 257 + j];
            ws[OFF_M + b * 61 + t] = s;
        }
    } else if (blk == 106) {
        if (t < 128) ws[OFF_GP2 + t] = 0.f;
    } else if (blk < 115) {
        float* slab = L;                       // [16][257]
        int w = blk - 107, v0 = w * 16;
        for (int g = t; g < 4096; g += 256)
            slab[(g >> 8) * 257 + (g & 255)] = Wf1[(v0 + (g >> 8)) * 256 + (g & 255)];
        __syncthreads();
        for (int g = t; g < 4096; g += 256) {
            int e = g >> 4, vl = g & 15;
            ws[OFF_WF1T + e * 128 + v0 + vl] = slab[vl * 257 + e];
        }
    } else if (blk < 179) {
        int b = blk - 115;
        float* red = L;
        float acc[126];
#pragma unroll
        for (int i = 0; i < 126; ++i) acc[i] = 0.f;
        for (int k = 0; k < 8; ++k) {
            int n = t + 256 * k;
            const float* xp = x + (size_t)(b * NPTS + n) * 10;
            float x0 = xp[0], x1 = xp[1], x2 = xp[2];
            float rn = x0 * x0 + x1 * x1 + x2 * x2;
            float inv = 1.f / (sqrtf(rn) + 1e-8f);
            float c[6];
            c[0] = fmaxf(x2, 0.f) * inv; c[1] = fmaxf(-x2, 0.f) * inv;
            c[2] = fmaxf(x1, 0.f) * inv; c[3] = fmaxf(-x1, 0.f) * inv;
            c[4] = fmaxf(x0, 0.f) * inv; c[5] = fmaxf(-x0, 0.f) * inv;
#pragma unroll
            for (int a = 0; a < 6; ++a) c[a] *= c[a];
            float xx[6] = {x0 * x0, x0 * x1, x0 * x2, x1 * x1, x1 * x2, x2 * x2};
#pragma unroll
            for (int a = 0; a < 6; ++a)
#pragma unroll
                for (int a2 = a; a2 < 6; ++a2) {
                    int p = a * 6 - (a * (a - 1)) / 2 + (a2 - a);
                    float cc = c[a] * c[a2];
#pragma unroll
                    for (int q = 0; q < 6; ++q)
                        acc[p * 6 + q] = fmaf(cc, xx[q], acc[p * 6 + q]);
                }
        }
#pragma unroll
        for (int i = 0; i < 61; ++i) red[i * 257 + t] = acc[i];
        __syncthreads();
        if (t < 61) {
            float s = 0.f;
#pragma unroll 8
            for (int j = 0; j < 256; ++j) s += red[t * 257 + j];
            ws[OFF_MOM + b * 240 + 108 + t] = s;
        }
        __syncthreads();
#pragma unroll
        for (int i = 0; i < 61; ++i) red[i * 257 + t] = acc[61 + i];
        __syncthreads();
        if (t < 61) {
            float s = 0.f;
#pragma unroll 8
            for (int j = 0; j < 256; ++j) s += red[t * 257 + j];
            ws[OFF_MOM + b * 240 + 108 + 61 + t] = s;
        }
        __syncthreads();
#pragma unroll
        for (int i = 0; i < 4; ++i) red[i * 257 + t] = acc[122 + i];
        __syncthreads();
        if (t < 4) {
            float s = 0.f;
#pragma unroll 8
            for (int j = 0; j < 256; ++j) s += red[t * 257 + j];
            ws[OFF_MOM + b * 240 + 108 + 122 + t] = s;
        }
    } else {
        int b = blk - 179;
        float* red = L;
        float acc[108];
#pragma unroll
        for (int i = 0; i < 108; ++i) acc[i] = 0.f;
        for (int k = 0; k < 8; ++k) {
            int n = t + 256 * k;
            const float* xp = x + (size_t)(b * NPTS + n) * 10;
            float x0 = xp[0], x1 = xp[1], x2 = xp[2];
            float rn = x0 * x0 + x1 * x1 + x2 * x2;
            float inv = 1.f / (sqrtf(rn) + 1e-8f);
            float c[6];
            c[0] = fmaxf(x2, 0.f) * inv; c[1] = fmaxf(-x2, 0.f) * inv;
            c[2] = fmaxf(x1, 0.f) * inv; c[3] = fmaxf(-x1, 0.f) * inv;
            c[4] = fmaxf(x0, 0.f) * inv; c[5] = fmaxf(-x0, 0.f) * inv;
#pragma unroll
            for (int a = 0; a < 6; ++a) c[a] *= c[a];
#pragma unroll
            for (int a = 0; a < 6; ++a) {
                acc[a] += c[a];
                acc[6 + a * 3 + 0] = fmaf(c[a], x0, acc[6 + a * 3 + 0]);
                acc[6 + a * 3 + 1] = fmaf(c[a], x1, acc[6 + a * 3 + 1]);
                acc[6 + a * 3 + 2] = fmaf(c[a], x2, acc[6 + a * 3 + 2]);
            }
#pragma unroll
            for (int a = 0; a < 6; ++a)
#pragma unroll
                for (int a2 = a; a2 < 6; ++a2) {
                    int p = a * 6 - (a * (a - 1)) / 2 + (a2 - a);
                    float cc = c[a] * c[a2];
                    acc[24 + p] += cc;
                    acc[45 + p * 3 + 0] = fmaf(cc, x0, acc[45 + p * 3 + 0]);
                    acc[45 + p * 3 + 1] = fmaf(cc, x1, acc[45 + p * 3 + 1]);
                    acc[45 + p * 3 + 2] = fmaf(cc, x2, acc[45 + p * 3 + 2]);
                }
        }
#pragma unroll
        for (int i = 0; i < 61; ++i) red[i * 257 + t] = acc[i];
        __syncthreads();
        if (t < 61) {
            float s = 0.f;
#pragma unroll 8
            for (int j = 0; j < 256; ++j) s += red[t * 257 + j];
            ws[OFF_MOM + b * 240 + t] = s;
        }
        __syncthreads();
#pragma unroll
        for (int i = 0; i < 47; ++i) red[i * 257 + t] = acc[61 + i];
        __syncthreads();
        if (t < 47) {
            float s = 0.f;
#pragma unroll 8
            for (int j = 0; j < 256; ++j) s += red[t * 257 + j];
            ws[OFF_MOM + b * 240 + 61 + t] = s;
        }
    }
}

// ---------------------------------------------------------------------------
// k_d2: 64 blocks; h1/bn1 redundant + d2/bn2 for 4 owned e-columns.
// Staging now REGISTER-BATCHED: all loads issued before any LDS write ->
// one latency wait instead of ~30 serial ones (fix for 44us @ 1.8% VALUBusy).
__global__ __launch_bounds__(256) void k_d2(const float* __restrict__ Wdir,
                                            const float* __restrict__ g1,
                                            const float* __restrict__ b1,
                                            const float* __restrict__ Wdir2,
                                            const float* __restrict__ g2,
                                            const float* __restrict__ b2,
                                            float* __restrict__ ws) {
    __shared__ float L[12704];
    float* Wd  = L;            // [64][61]
    float* Ml  = L + 3904;     // [64][61]
    float* h1  = L + 7808;     // [64][65]
    float* wt2 = L + 11968;    // [4][65]
    float* d2l = L + 12228;    // [64][5]
    float* sc  = L + 12548;    // [64]
    float* of  = L + 12612;    // [64]
    float* scl = L + 12676;    // [4]
    float* ofl = L + 12680;    // [4]
    int blk = blockIdx.x, t = threadIdx.x;
    int e_base = blk * 4;
    // batched staging: issue ALL global loads first (independent), then write
    {
        float tm[15], tw[15];
#pragma unroll
        for (int i = 0; i < 15; ++i) tm[i] = ws[OFF_M + t + i * 256];
        float tmt = (t < 64) ? ws[OFF_M + 3840 + t] : 0.f;
#pragma unroll
        for (int i = 0; i < 15; ++i) tw[i] = Wdir[t + i * 256];
        float w2v = (t < 256) ? Wdir2[(e_base + (t >> 6)) * 64 + (t & 63)] : 0.f;
#pragma unroll
        for (int i = 0; i < 15; ++i) Ml[t + i * 256] = tm[i];
        if (t < 64) Ml[3840 + t] = tmt;
#pragma unroll
        for (int i = 0; i < 15; ++i) {
            int g = t + i * 256;
            Wd[(g / 60) * 61 + g % 60] = tw[i];
        }
        wt2[(t >> 6) * 65 + (t & 63)] = w2v;
    }
    __syncthreads();
    int m = t & 63;
    float Wr[60];
#pragma unroll
    for (int r = 0; r < 60; ++r) Wr[r] = Wd[m * 61 + r];
#pragma unroll
    for (int k = 0; k < 16; ++k) {
        int idx = t + 256 * k;
        int b = idx >> 6;
        const float* Mb = Ml + b * 61;
        float s = 0.f;
#pragma unroll
        for (int a = 0; a < 6; ++a)
#pragma unroll
            for (int c = 0; c < 10; ++c)
                s = fmaf(Wr[a * 10 + c], Mb[c * 6 + a], s);
        h1[b * 65 + m] = s / Mb[60];
    }
    __syncthreads();
    if (t < 64) {
        float s = 0.f, q = 0.f;
#pragma unroll 8
        for (int b = 0; b < 64; ++b) { float v = h1[b * 65 + t]; s += v; q = fmaf(v, v, q); }
        float mean = s * (1.f / 64.f);
        float var = q * (1.f / 64.f) - mean * mean;
        float scale = g1[t] * rsqrtf(var + 1e-5f);
        sc[t] = scale; of[t] = b1[t] - mean * scale;
    }
    __syncthreads();
#pragma unroll
    for (int k = 0; k < 16; ++k) {
        int idx = t + 256 * k;
        int b = idx >> 6;
        h1[b * 65 + m] = fmaxf(fmaf(h1[b * 65 + m], sc[m], of[m]), 0.f);
    }
    __syncthreads();
    {
        int b = t >> 2, el = t & 3;
        const float* h = h1 + b * 65;
        const float* w = wt2 + el * 65;
        float s = 0.f;
#pragma unroll
        for (int mm = 0; mm < 64; ++mm) s = fmaf(h[mm], w[mm], s);
        d2l[b * 5 + el] = s;
    }
    __syncthreads();
    if (t < 4) {
        float s = 0.f, q = 0.f;
#pragma unroll 8
        for (int b = 0; b < 64; ++b) { float v = d2l[b * 5 + t]; s += v; q = fmaf(v, v, q); }
        float mean = s * (1.f / 64.f);
        float var = q * (1.f / 64.f) - mean * mean;
        int E = e_base + t;
        float scale = g2[E] * rsqrtf(var + 1e-5f);
        scl[t] = scale; ofl[t] = b2[E] - mean * scale;
    }
    __syncthreads();
    {
        int b = t >> 2, el = t & 3;
        float v = fmaxf(fmaf(d2l[b * 5 + el], scl[el], ofl[el]), 0.f);
        ws[OFF_D2P + b * 256 + e_base + el] = v;
    }
}

// ---------------------------------------------------------------------------
// k_z: one block per batch: z, U2, C2, closed-form bn3 S/Q + point-0
// correction -> GP2. Staging register-batched (wcm was 17 serial iters).
__global__ __launch_bounds__(512) void k_z(const float* __restrict__ x,
                                           const float* __restrict__ bf1,
                                           const float* __restrict__ Wcm,
                                           const float* __restrict__ bcm,
                                           float* __restrict__ ws) {
    __shared__ float L[11252];
    float* d2row = L;          // [256]
    float* T2l   = L + 256;    // [1152]
    float* zp    = L + 1408;   // [4][128]
    float* zl    = L + 1920;   // [128]
    float* U2l   = L + 2048;   // [384]
    float* C2l   = L + 2432;   // [64]
    float* mom   = L + 2496;   // [240]
    float* x0l   = L + 2736;   // [4]
    float* wl    = L + 2740;   // [64][133] Wcm padded
    int b = blockIdx.x, t = threadIdx.x;
    // batched staging: issue all loads before any LDS write
    {
        float tc[16];
#pragma unroll
        for (int i = 0; i < 16; ++i) tc[i] = Wcm[t + i * 512];
        float tct = (t < 192) ? Wcm[8192 + t] : 0.f;
        float td  = (t < 256) ? ws[OFF_D2P + b * 256 + t] : 0.f;
        float tt0 = ws[OFF_T2 + t];
        float tt1 = ws[OFF_T2 + 512 + t];
        float tt2 = (t < 128) ? ws[OFF_T2 + 1024 + t] : 0.f;
        float tmo = (t < 234) ? ws[OFF_MOM + b * 240 + t] : 0.f;
        float tx  = (t < 3) ? x[(size_t)b * NPTS * 10 + t] : 0.f;
#pragma unroll
        for (int i = 0; i < 16; ++i) {
            int g = t + i * 512;
            wl[(g / 131) * 133 + g % 131] = tc[i];
        }
        if (t < 192) { int g = 8192 + t; wl[(g / 131) * 133 + g % 131] = tct; }
        if (t < 256) d2row[t] = td;
        T2l[t] = tt0;
        T2l[512 + t] = tt1;
        if (t < 128) T2l[1024 + t] = tt2;
        if (t < 234) mom[t] = tmo;
        if (t < 3) x0l[t] = tx;
    }
    __syncthreads();
    // z partials: q = t>>7 owns e in [64q, 64q+64)
    {
        int q = t >> 7, v = t & 127;
        const float* Wt = ws + OFF_WF1T + (q * 64) * 128 + v;
        const float* d = d2row + q * 64;
        float s = 0.f;
#pragma unroll 8
        for (int e = 0; e < 64; ++e) s = fmaf(d[e], Wt[e * 128], s);
        zp[q * 128 + v] = s;
    }
    __syncthreads();
    if (t < 128)
        zl[t] = bf1[t] + ((zp[t] + zp[128 + t]) + (zp[256 + t] + zp[384 + t]));
    __syncthreads();
    if (t < 384) {
        const float* Vt = ws + OFF_V;
        float s0 = 0.f;
#pragma unroll 8
        for (int v = 0; v < 128; ++v) s0 = fmaf(zl[v], Vt[v * 384 + t], s0);
        U2l[t] = s0;
        ws[OFF_U2 + b * 384 + t] = s0;
    } else if (t < 448) {
        int m = t - 384;
        const float* w = wl + m * 133;
        float s = bcm[m];
#pragma unroll 4
        for (int i = 0; i < 128; ++i) s = fmaf(zl[i], w[i], s);
        s = fmaf(x0l[0], w[128], s);
        s = fmaf(x0l[1], w[129], s);
        s = fmaf(x0l[2], w[130], s);
        ws[OFF_C2 + b * 64 + m] = s;
        C2l[m] = s;
    }
    __syncthreads();
    // closed-form S/Q contraction; one thread per m
    if (t < 64) {
        int m = t;
        float T[18], U[6];
#pragma unroll
        for (int r = 0; r < 18; ++r) T[r] = T2l[m * 18 + r];
#pragma unroll
        for (int a = 0; a < 6; ++a) U[a] = U2l[m * 6 + a];
        float S = 0.f;
#pragma unroll
        for (int a = 0; a < 6; ++a) {
            S = fmaf(mom[6 + a * 3 + 0], T[a * 3 + 0], S);
            S = fmaf(mom[6 + a * 3 + 1], T[a * 3 + 1], S);
            S = fmaf(mom[6 + a * 3 + 2], T[a * 3 + 2], S);
            S = fmaf(mom[a], U[a], S);
        }
        float qd = 0.f, qo = 0.f;
#pragma unroll
        for (int a = 0; a < 6; ++a)
#pragma unroll
            for (int a2 = a; a2 < 6; ++a2) {
                int p = a * 6 - (a * (a - 1)) / 2 + (a2 - a);
                const float* b3 = mom + 108 + p * 6;   // (00,01,02,11,12,22)
                const float* b2m = mom + 45 + p * 3;
                float b1v = mom[24 + p];
                float Ta0 = T[a * 3], Ta1 = T[a * 3 + 1], Ta2 = T[a * 3 + 2];
                float Tb0 = T[a2 * 3], Tb1 = T[a2 * 3 + 1], Tb2 = T[a2 * 3 + 2];
                float w0 = b3[0] * Ta0 + b3[1] * Ta1 + b3[2] * Ta2;
                float w1 = b3[1] * Ta0 + b3[3] * Ta1 + b3[4] * Ta2;
                float w2 = b3[2] * Ta0 + b3[4] * Ta1 + b3[5] * Ta2;
                float term = w0 * Tb0 + w1 * Tb1 + w2 * Tb2;
                float d1 = b2m[0] * Ta0 + b2m[1] * Ta1 + b2m[2] * Ta2;
                float d2_ = b2m[0] * Tb0 + b2m[1] * Tb1 + b2m[2] * Tb2;
                term += U[a2] * d1 + U[a] * d2_ + U[a] * U[a2] * b1v;
                if (a == a2) qd += term; else qo += term;
            }
        float Q = qd + 2.f * qo;
        float xx0 = x0l[0], xx1 = x0l[1], xx2 = x0l[2];
        float rn = xx0 * xx0 + xx1 * xx1 + xx2 * xx2;
        float inv = 1.f / (sqrtf(rn) + 1e-8f);
        float c2[6];
        c2[0] = fmaxf(xx2, 0.f) * inv; c2[1] = fmaxf(-xx2, 0.f) * inv;
        c2[2] = fmaxf(xx1, 0.f) * inv; c2[3] = fmaxf(-xx1, 0.f) * inv;
        c2[4] = fmaxf(xx0, 0.f) * inv; c2[5] = fmaxf(-xx0, 0.f) * inv;
        float h0 = 0.f;
#pragma unroll
        for (int a = 0; a < 6; ++a) {
            float cc = c2[a] * c2[a];
            float ta = fmaf(xx0, T[a * 3], fmaf(xx1, T[a * 3 + 1], fmaf(xx2, T[a * 3 + 2], U[a])));
            h0 = fmaf(cc, ta, h0);
        }
        float C2v = C2l[m];
        S += C2v - h0;
        Q += C2v * C2v - h0 * h0;
        atomicAdd(&ws[OFF_GP2 + m], S);
        atomicAdd(&ws[OFF_GP2 + 64 + m], Q);
    }
}

// ---------------------------------------------------------------------------
// k_e: epilogue; per-block bn3 scale/off from the single GP2 row (identical
// FP order in every block -> deterministic).
__global__ __launch_bounds__(512) void k_e(const float* __restrict__ x,
                                           const float* __restrict__ g3,
                                           const float* __restrict__ b3,
                                           const float* __restrict__ Wf2,
                                           const float* __restrict__ bf2,
                                           const float* __restrict__ ws,
                                           float* __restrict__ out) {
    __shared__ __attribute__((aligned(16))) float L[6464];
    float* Wl24 = L;           // [64][24]: {T2 at a*4+j, U2 at a*4+3}
    float* Pl   = L + 1536;    // [64][12]: {Wf2[0..6], scale@7, off@8}
    float* C2l  = L + 2304;    // [64]
    float* yp   = L + 2368;    // [256][16]
    int blk = blockIdx.x, t = threadIdx.x;
    int b = blk >> 3;
    for (int g = t; g < 1152; g += 512) {
        int m = g / 18, r = g % 18, a = r / 3, j = r % 3;
        Wl24[m * 24 + a * 4 + j] = ws[OFF_T2 + g];
    }
    if (t < 384)
        Wl24[(t / 6) * 24 + (t % 6) * 4 + 3] = ws[OFF_U2 + b * 384 + t];
    if (t < 448) {
        int m = t / 7, k = t % 7;
        Pl[m * 12 + k] = Wf2[k * 64 + m];
    }
    if (t < 64) {
        float S = ws[OFF_GP2 + t];
        float Q = ws[OFF_GP2 + 64 + t];
        float mean = S * (1.f / 131072.f);
        float var = Q * (1.f / 131072.f) - mean * mean;
        float scale = g3[t] * rsqrtf(var + 1e-5f);
        Pl[t * 12 + 7] = scale;
        Pl[t * 12 + 8] = b3[t] - mean * scale;
    }
    if ((blk & 7) == 0 && t < 64) C2l[t] = ws[OFF_C2 + b * 64 + t];
    __syncthreads();

    int p_loc = t >> 1, mh = t & 1;
    int p = blk * 256 + p_loc;
    const float* xp = x + (size_t)p * 10;
    float x0 = xp[0], x1 = xp[1], x2 = xp[2];
    float rn = x0 * x0 + x1 * x1 + x2 * x2;
    float inv = 1.f / (sqrtf(rn) + 1e-8f);
    float c2[6];
    c2[0] = fmaxf(x2, 0.f) * inv; c2[1] = fmaxf(-x2, 0.f) * inv;
    c2[2] = fmaxf(x1, 0.f) * inv; c2[3] = fmaxf(-x1, 0.f) * inv;
    c2[4] = fmaxf(x0, 0.f) * inv; c2[5] = fmaxf(-x0, 0.f) * inv;
#pragma unroll
    for (int a = 0; a < 6; ++a) c2[a] *= c2[a];
    bool c0 = ((p & 2047) == 0);
    float y[7];
#pragma unroll
    for (int k = 0; k < 7; ++k) y[k] = mh ? 0.f : bf2[k];
    int m0 = mh * 32;
#pragma unroll 4
    for (int mm = 0; mm < 32; ++mm) {
        int m = m0 + mm;
        const float4* Wm = (const float4*)(Wl24 + m * 24);
        float h = 0.f;
#pragma unroll
        for (int a = 0; a < 6; ++a) {
            float4 wq = Wm[a];   // {T0,T1,T2,U}
            float ta = fmaf(x0, wq.x, fmaf(x1, wq.y, fmaf(x2, wq.z, wq.w)));
            h = fmaf(c2[a], ta, h);
        }
        if (c0) h = C2l[m];
        const float4* Pm = (const float4*)(Pl + m * 12);
        float4 p0 = Pm[0], p1 = Pm[1];
        float offv = Pl[m * 12 + 8];
        float r = fmaxf(fmaf(h, p1.w, offv), 0.f);
        y[0] = fmaf(r, p0.x, y[0]); y[1] = fmaf(r, p0.y, y[1]);
        y[2] = fmaf(r, p0.z, y[2]); y[3] = fmaf(r, p0.w, y[3]);
        y[4] = fmaf(r, p1.x, y[4]); y[5] = fmaf(r, p1.y, y[5]);
        y[6] = fmaf(r, p1.z, y[6]);
    }
#pragma unroll
    for (int k = 0; k < 7; ++k) yp[p_loc * 16 + mh * 8 + k] = y[k];
    __syncthreads();
    float* op = out + (size_t)blk * 1792;
    for (int g = t; g < 1792; g += 512) {
        int pp = g / 7, k = g % 7;
        float v = yp[pp * 16 + k] + yp[pp * 16 + 8 + k];
        op[g] = 1.f / (1.f + __expf(-v));
    }
}

// ---------------------------------------------------------------------------
extern "C" void kernel_launch(void* const* d_in, const int* in_sizes, int n_in,
                              void* d_out, int out_size, void* d_ws, size_t ws_size,
                              hipStream_t stream) {
    const float* x     = (const float*)d_in[0];
    // d_in[1]=Wc, d_in[2]=bc : dead code in reference
    const float* Wdir  = (const float*)d_in[3];
    const float* g1    = (const float*)d_in[4];
    const float* b1    = (const float*)d_in[5];
    const float* Wdir2 = (const float*)d_in[6];
    const float* g2    = (const float*)d_in[7];
    const float* b2    = (const float*)d_in[8];
    const float* Wf1   = (const float*)d_in[9];
    const float* bf1   = (const float*)d_in[10];
    const float* Wcm   = (const float*)d_in[11];
    const float* bcm   = (const float*)d_in[12];
    const float* Wdc   = (const float*)d_in[13];
    const float* Wm0   = (const float*)d_in[14];
    const float* g3    = (const float*)d_in[15];
    const float* b3    = (const float*)d_in[16];
    const float* Wf2   = (const float*)d_in[17];
    const float* bf2   = (const float*)d_in[18];
    float* ws  = (float*)d_ws;
    float* out = (float*)d_out;

    k_wa <<<243, 256, 0, stream>>>(x, Wm0, Wdc, Wf1, ws);
    k_d2 <<<64,  256, 0, stream>>>(Wdir, g1, b1, Wdir2, g2, b2, ws);
    k_z  <<<64,  512, 0, stream>>>(x, bf1, Wcm, bcm, ws);
    k_e  <<<512, 512, 0, stream>>>(x, g3, b3, Wf2, bf2, ws, out);
}

// Round 12
// 148.684 us; speedup vs baseline: 1.3407x; 1.0699x over previous
//
#include <hip/hip_runtime.h>
#include <math.h>

// Problem constants
#define BATCH 64
#define NPTS  2048
// ws float offsets
#define OFF_M    0       // [64][61] M[b][c*6+a], Sdw at [b][60] (dead after k_d2)
#define OFF_T2   4096    // [64][18]  T2[m][a*3+j]
#define OFF_GP2  5248    // [128] S[64], Q[64] (atomic, zeroed by k_wa)
#define OFF_V    8192    // TRANSPOSED: Vt[v][ma] = [128][384]
#define OFF_WF1T 57344   // Wf1 transposed: [256 e][128 v]
#define OFF_D2P  90112   // [64][256] relu(bn2(d2))
#define OFF_C2   114688  // [64][64]  center2[b][m] (written by k_z)
#define OFF_U2   118784  // [64][384] U2[b][ma] (written by k_z)
#define OFF_MOM  143360  // [64][240] per-batch moments: A1[6],A2[18],B1[21],B2[63],B3[126]

// ---------------------------------------------------------------------------
// k_wa: blocks 0..23    fold-V as tiled GEMM (a, v-quarter), SW-pipelined
//       blocks 24..41   fold-T2 (one (a,j) pair per block)
//       blocks 42..105  stage-A per-batch moments (M, dw-weighted)
//       block 106       zero GP2
//       blocks 107..114 transpose Wf1 -> Wf1t
//       blocks 115..178 bn3 moments group0: B3
//       blocks 179..242 bn3 moments group1: A1,A2,B1,B2
__global__ __launch_bounds__(256) void k_wa(const float* __restrict__ x,
                                            const float* __restrict__ Wm0,
                                            const float* __restrict__ Wdc,
                                            const float* __restrict__ Wf1,
                                            float* __restrict__ ws) {
    __shared__ __attribute__((aligned(16))) float L[61 * 257];
    int blk = blockIdx.x, t = threadIdx.x;
    if (blk < 24) {
        // fold V, software-pipelined: reg-load tile k+1 while computing tile k
        float* wml = L;            // [64][33]
        float* pl  = L + 2112;     // [32][36]
        int a = blk >> 2, vq = blk & 3;
        int m = t & 63, vg = t >> 6;
        float acc[8];
#pragma unroll
        for (int i = 0; i < 8; ++i) acc[i] = 0.f;
        float rm[8], rp[4];
#pragma unroll
        for (int i = 0; i < 8; ++i) {
            int g = t + 256 * i;
            rm[i] = Wm0[(g >> 5) * 256 + (g & 31)];
        }
#pragma unroll
        for (int i = 0; i < 4; ++i) {
            int g = t + 256 * i;
            rp[i] = Wdc[((g >> 5) * 6 + a) * 131 + 3 + vq * 32 + (g & 31)];
        }
        for (int tile = 0; tile < 8; ++tile) {
#pragma unroll
            for (int i = 0; i < 8; ++i) {
                int g = t + 256 * i;
                wml[(g >> 5) * 33 + (g & 31)] = rm[i];
            }
#pragma unroll
            for (int i = 0; i < 4; ++i) {
                int g = t + 256 * i;
                pl[(g >> 5) * 36 + (g & 31)] = rp[i];
            }
            __syncthreads();
            if (tile < 7) {
                int e1 = (tile + 1) * 32;
#pragma unroll
                for (int i = 0; i < 8; ++i) {
                    int g = t + 256 * i;
                    rm[i] = Wm0[(g >> 5) * 256 + e1 + (g & 31)];
                }
#pragma unroll
                for (int i = 0; i < 4; ++i) {
                    int g = t + 256 * i;
                    rp[i] = Wdc[((e1 + (g >> 5)) * 6 + a) * 131 + 3 + vq * 32 + (g & 31)];
                }
            }
#pragma unroll
            for (int e = 0; e < 32; ++e) {
                float wv = wml[m * 33 + e];
                const float4* p4 = (const float4*)(pl + e * 36 + vg * 8);
                float4 pa = p4[0], pb = p4[1];
                acc[0] = fmaf(wv, pa.x, acc[0]); acc[1] = fmaf(wv, pa.y, acc[1]);
                acc[2] = fmaf(wv, pa.z, acc[2]); acc[3] = fmaf(wv, pa.w, acc[3]);
                acc[4] = fmaf(wv, pb.x, acc[4]); acc[5] = fmaf(wv, pb.y, acc[5]);
                acc[6] = fmaf(wv, pb.z, acc[6]); acc[7] = fmaf(wv, pb.w, acc[7]);
            }
            __syncthreads();
        }
#pragma unroll
        for (int vv = 0; vv < 8; ++vv)
            ws[OFF_V + (vq * 32 + vg * 8 + vv) * 384 + m * 6 + a] = acc[vv];
    } else if (blk < 42) {
        float* col = L;
        float* red = L + 256;
        int p = blk - 24, a = p / 3, j = p % 3;
        col[t] = Wdc[(t * 6 + a) * 131 + j];
        __syncthreads();
        int m = t >> 2, q = t & 3;
        const float* wm = Wm0 + m * 256 + q * 64;
        const float* cl = col + q * 64;
        float s = 0.f;
#pragma unroll 8
        for (int i = 0; i < 64; ++i) s = fmaf(wm[i], cl[i], s);
        red[t] = s;
        __syncthreads();
        if (t < 64) {
            float v = (red[t * 4] + red[t * 4 + 1]) + (red[t * 4 + 2] + red[t * 4 + 3]);
            ws[OFF_T2 + t * 18 + a * 3 + j] = v;
        }
    } else if (blk < 106) {
        int b = blk - 42;
        float* red = L;                        // [61][257]
        float acc[61];
#pragma unroll
        for (int i = 0; i < 61; ++i) acc[i] = 0.f;
#pragma unroll 2
        for (int k = 0; k < 8; ++k) {
            int n = t + 256 * k;
            const float* xp = x + (size_t)(b * NPTS + n) * 10;
            float xv[10];
#pragma unroll
            for (int j = 0; j < 5; ++j) {
                float2 v = *(const float2*)(xp + 2 * j);
                xv[2 * j] = v.x; xv[2 * j + 1] = v.y;
            }
            float x0 = xv[0], x1 = xv[1], x2 = xv[2];
            float rn = x0 * x0 + x1 * x1 + x2 * x2;
            float norm = sqrtf(rn);
            float inv = 1.f / (norm + 1e-8f);
            float c2[6];
            c2[0] = fmaxf(x2, 0.f) * inv; c2[1] = fmaxf(-x2, 0.f) * inv;
            c2[2] = fmaxf(x1, 0.f) * inv; c2[3] = fmaxf(-x1, 0.f) * inv;
            c2[4] = fmaxf(x0, 0.f) * inv; c2[5] = fmaxf(-x0, 0.f) * inv;
#pragma unroll
            for (int a = 0; a < 6; ++a) c2[a] *= c2[a];
            float dw = 1.f - (rn - 1.f) * (1.f / 3.f);
            if (dw < 0.f) dw = 0.f;
            if (norm <= 0.f) dw = 0.f;
            float cw[6];
#pragma unroll
            for (int a = 0; a < 6; ++a) cw[a] = c2[a] * dw;
#pragma unroll
            for (int c = 0; c < 10; ++c) {
                float dv = (c < 7) ? xv[3 + c] : xv[c - 7];
#pragma unroll
                for (int a = 0; a < 6; ++a)
                    acc[c * 6 + a] = fmaf(dv, cw[a], acc[c * 6 + a]);
            }
            acc[60] += dw;
        }
#pragma unroll
        for (int i = 0; i < 61; ++i) red[i * 257 + t] = acc[i];
        __syncthreads();
        if (t < 61) {
            float s = 0.f;
#pragma unroll 8
            for (int j = 0; j < 256; ++j) s += red[t * 257 + j];
            ws[OFF_M + b * 61 + t] = s;
        }
    } else if (blk == 106) {
        if (t < 128) ws[OFF_GP2 + t] = 0.f;
    } else if (blk < 115) {
        float* slab = L;                       // [16][257]
        int w = blk - 107, v0 = w * 16;
        for (int g = t; g < 4096; g += 256)
            slab[(g >> 8) * 257 + (g & 255)] = Wf1[(v0 + (g >> 8)) * 256 + (g & 255)];
        __syncthreads();
        for (int g = t; g < 4096; g += 256) {
            int e = g >> 4, vl = g & 15;
            ws[OFF_WF1T + e * 128 + v0 + vl] = slab[vl * 257 + e];
        }
    } else if (blk < 179) {
        int b = blk - 115;
        float* red = L;
        float acc[126];
#pragma unroll
        for (int i = 0; i < 126; ++i) acc[i] = 0.f;
#pragma unroll 2
        for (int k = 0; k < 8; ++k) {
            int n = t + 256 * k;
            const float* xp = x + (size_t)(b * NPTS + n) * 10;
            float x0 = xp[0], x1 = xp[1], x2 = xp[2];
            float rn = x0 * x0 + x1 * x1 + x2 * x2;
            float inv = 1.f / (sqrtf(rn) + 1e-8f);
            float c[6];
            c[0] = fmaxf(x2, 0.f) * inv; c[1] = fmaxf(-x2, 0.f) * inv;
            c[2] = fmaxf(x1, 0.f) * inv; c[3] = fmaxf(-x1, 0.f) * inv;
            c[4] = fmaxf(x0, 0.f) * inv; c[5] = fmaxf(-x0, 0.f) * inv;
#pragma unroll
            for (int a = 0; a < 6; ++a) c[a] *= c[a];
            float xx[6] = {x0 * x0, x0 * x1, x0 * x2, x1 * x1, x1 * x2, x2 * x2};
#pragma unroll
            for (int a = 0; a < 6; ++a)
#pragma unroll
                for (int a2 = a; a2 < 6; ++a2) {
                    int p = a * 6 - (a * (a - 1)) / 2 + (a2 - a);
                    float cc = c[a] * c[a2];
#pragma unroll
                    for (int q = 0; q < 6; ++q)
                        acc[p * 6 + q] = fmaf(cc, xx[q], acc[p * 6 + q]);
                }
        }
#pragma unroll
        for (int i = 0; i < 61; ++i) red[i * 257 + t] = acc[i];
        __syncthreads();
        if (t < 61) {
            float s = 0.f;
#pragma unroll 8
            for (int j = 0; j < 256; ++j) s += red[t * 257 + j];
            ws[OFF_MOM + b * 240 + 108 + t] = s;
        }
        __syncthreads();
#pragma unroll
        for (int i = 0; i < 61; ++i) red[i * 257 + t] = acc[61 + i];
        __syncthreads();
        if (t < 61) {
            float s = 0.f;
#pragma unroll 8
            for (int j = 0; j < 256; ++j) s += red[t * 257 + j];
            ws[OFF_MOM + b * 240 + 108 + 61 + t] = s;
        }
        __syncthreads();
#pragma unroll
        for (int i = 0; i < 4; ++i) red[i * 257 + t] = acc[122 + i];
        __syncthreads();
        if (t < 4) {
            float s = 0.f;
#pragma unroll 8
            for (int j = 0; j < 256; ++j) s += red[t * 257 + j];
            ws[OFF_MOM + b * 240 + 108 + 122 + t] = s;
        }
    } else {
        int b = blk - 179;
        float* red = L;
        float acc[108];
#pragma unroll
        for (int i = 0; i < 108; ++i) acc[i] = 0.f;
#pragma unroll 2
        for (int k = 0; k < 8; ++k) {
            int n = t + 256 * k;
            const float* xp = x + (size_t)(b * NPTS + n) * 10;
            float x0 = xp[0], x1 = xp[1], x2 = xp[2];
            float rn = x0 * x0 + x1 * x1 + x2 * x2;
            float inv = 1.f / (sqrtf(rn) + 1e-8f);
            float c[6];
            c[0] = fmaxf(x2, 0.f) * inv; c[1] = fmaxf(-x2, 0.f) * inv;
            c[2] = fmaxf(x1, 0.f) * inv; c[3] = fmaxf(-x1, 0.f) * inv;
            c[4] = fmaxf(x0, 0.f) * inv; c[5] = fmaxf(-x0, 0.f) * inv;
#pragma unroll
            for (int a = 0; a < 6; ++a) c[a] *= c[a];
#pragma unroll
            for (int a = 0; a < 6; ++a) {
                acc[a] += c[a];
                acc[6 + a * 3 + 0] = fmaf(c[a], x0, acc[6 + a * 3 + 0]);
                acc[6 + a * 3 + 1] = fmaf(c[a], x1, acc[6 + a * 3 + 1]);
                acc[6 + a * 3 + 2] = fmaf(c[a], x2, acc[6 + a * 3 + 2]);
            }
#pragma unroll
            for (int a = 0; a < 6; ++a)
#pragma unroll
                for (int a2 = a; a2 < 6; ++a2) {
                    int p = a * 6 - (a * (a - 1)) / 2 + (a2 - a);
                    float cc = c[a] * c[a2];
                    acc[24 + p] += cc;
                    acc[45 + p * 3 + 0] = fmaf(cc, x0, acc[45 + p * 3 + 0]);
                    acc[45 + p * 3 + 1] = fmaf(cc, x1, acc[45 + p * 3 + 1]);
                    acc[45 + p * 3 + 2] = fmaf(cc, x2, acc[45 + p * 3 + 2]);
                }
        }
#pragma unroll
        for (int i = 0; i < 61; ++i) red[i * 257 + t] = acc[i];
        __syncthreads();
        if (t < 61) {
            float s = 0.f;
#pragma unroll 8
            for (int j = 0; j < 256; ++j) s += red[t * 257 + j];
            ws[OFF_MOM + b * 240 + t] = s;
        }
        __syncthreads();
#pragma unroll
        for (int i = 0; i < 47; ++i) red[i * 257 + t] = acc[61 + i];
        __syncthreads();
        if (t < 47) {
            float s = 0.f;
#pragma unroll 8
            for (int j = 0; j < 256; ++j) s += red[t * 257 + j];
            ws[OFF_MOM + b * 240 + 61 + t] = s;
        }
    }
}

// ---------------------------------------------------------------------------
// k_d2: 64 blocks; h1/bn1 redundant + d2/bn2 for 4 owned e-columns.
// Staging register-batched (proven round 11).
__global__ __launch_bounds__(256) void k_d2(const float* __restrict__ Wdir,
                                            const float* __restrict__ g1,
                                            const float* __restrict__ b1,
                                            const float* __restrict__ Wdir2,
                                            const float* __restrict__ g2,
                                            const float* __restrict__ b2,
                                            float* __restrict__ ws) {
    __shared__ float L[12704];
    float* Wd  = L;            // [64][61]
    float* Ml  = L + 3904;     // [64][61]
    float* h1  = L + 7808;     // [64][65]
    float* wt2 = L + 11968;    // [4][65]
    float* d2l = L + 12228;    // [64][5]
    float* sc  = L + 12548;    // [64]
    float* of  = L + 12612;    // [64]
    float* scl = L + 12676;    // [4]
    float* ofl = L + 12680;    // [4]
    int blk = blockIdx.x, t = threadIdx.x;
    int e_base = blk * 4;
    {
        float tm[15], tw[15];
#pragma unroll
        for (int i = 0; i < 15; ++i) tm[i] = ws[OFF_M + t + i * 256];
        float tmt = (t < 64) ? ws[OFF_M + 3840 + t] : 0.f;
#pragma unroll
        for (int i = 0; i < 15; ++i) tw[i] = Wdir[t + i * 256];
        float w2v = (t < 256) ? Wdir2[(e_base + (t >> 6)) * 64 + (t & 63)] : 0.f;
#pragma unroll
        for (int i = 0; i < 15; ++i) Ml[t + i * 256] = tm[i];
        if (t < 64) Ml[3840 + t] = tmt;
#pragma unroll
        for (int i = 0; i < 15; ++i) {
            int g = t + i * 256;
            Wd[(g / 60) * 61 + g % 60] = tw[i];
        }
        wt2[(t >> 6) * 65 + (t & 63)] = w2v;
    }
    __syncthreads();
    int m = t & 63;
    float Wr[60];
#pragma unroll
    for (int r = 0; r < 60; ++r) Wr[r] = Wd[m * 61 + r];
#pragma unroll
    for (int k = 0; k < 16; ++k) {
        int idx = t + 256 * k;
        int b = idx >> 6;
        const float* Mb = Ml + b * 61;
        float s = 0.f;
#pragma unroll
        for (int a = 0; a < 6; ++a)
#pragma unroll
            for (int c = 0; c < 10; ++c)
                s = fmaf(Wr[a * 10 + c], Mb[c * 6 + a], s);
        h1[b * 65 + m] = s / Mb[60];
    }
    __syncthreads();
    if (t < 64) {
        float s = 0.f, q = 0.f;
#pragma unroll 8
        for (int b = 0; b < 64; ++b) { float v = h1[b * 65 + t]; s += v; q = fmaf(v, v, q); }
        float mean = s * (1.f / 64.f);
        float var = q * (1.f / 64.f) - mean * mean;
        float scale = g1[t] * rsqrtf(var + 1e-5f);
        sc[t] = scale; of[t] = b1[t] - mean * scale;
    }
    __syncthreads();
#pragma unroll
    for (int k = 0; k < 16; ++k) {
        int idx = t + 256 * k;
        int b = idx >> 6;
        h1[b * 65 + m] = fmaxf(fmaf(h1[b * 65 + m], sc[m], of[m]), 0.f);
    }
    __syncthreads();
    {
        int b = t >> 2, el = t & 3;
        const float* h = h1 + b * 65;
        const float* w = wt2 + el * 65;
        float s = 0.f;
#pragma unroll
        for (int mm = 0; mm < 64; ++mm) s = fmaf(h[mm], w[mm], s);
        d2l[b * 5 + el] = s;
    }
    __syncthreads();
    if (t < 4) {
        float s = 0.f, q = 0.f;
#pragma unroll 8
        for (int b = 0; b < 64; ++b) { float v = d2l[b * 5 + t]; s += v; q = fmaf(v, v, q); }
        float mean = s * (1.f / 64.f);
        float var = q * (1.f / 64.f) - mean * mean;
        int E = e_base + t;
        float scale = g2[E] * rsqrtf(var + 1e-5f);
        scl[t] = scale; ofl[t] = b2[E] - mean * scale;
    }
    __syncthreads();
    {
        int b = t >> 2, el = t & 3;
        float v = fmaxf(fmaf(d2l[b * 5 + el], scl[el], ofl[el]), 0.f);
        ws[OFF_D2P + b * 256 + e_base + el] = v;
    }
}

// ---------------------------------------------------------------------------
// k_z: one block per batch: z, U2, C2, closed-form bn3 S/Q + point-0
// correction -> GP2. Staging register-batched (proven round 11).
__global__ __launch_bounds__(512) void k_z(const float* __restrict__ x,
                                           const float* __restrict__ bf1,
                                           const float* __restrict__ Wcm,
                                           const float* __restrict__ bcm,
                                           float* __restrict__ ws) {
    __shared__ float L[11252];
    float* d2row = L;          // [256]
    float* T2l   = L + 256;    // [1152]
    float* zp    = L + 1408;   // [4][128]
    float* zl    = L + 1920;   // [128]
    float* U2l   = L + 2048;   // [384]
    float* C2l   = L + 2432;   // [64]
    float* mom   = L + 2496;   // [240]
    float* x0l   = L + 2736;   // [4]
    float* wl    = L + 2740;   // [64][133] Wcm padded
    int b = blockIdx.x, t = threadIdx.x;
    {
        float tc[16];
#pragma unroll
        for (int i = 0; i < 16; ++i) tc[i] = Wcm[t + i * 512];
        float tct = (t < 192) ? Wcm[8192 + t] : 0.f;
        float td  = (t < 256) ? ws[OFF_D2P + b * 256 + t] : 0.f;
        float tt0 = ws[OFF_T2 + t];
        float tt1 = ws[OFF_T2 + 512 + t];
        float tt2 = (t < 128) ? ws[OFF_T2 + 1024 + t] : 0.f;
        float tmo = (t < 234) ? ws[OFF_MOM + b * 240 + t] : 0.f;
        float tx  = (t < 3) ? x[(size_t)b * NPTS * 10 + t] : 0.f;
#pragma unroll
        for (int i = 0; i < 16; ++i) {
            int g = t + i * 512;
            wl[(g / 131) * 133 + g % 131] = tc[i];
        }
        if (t < 192) { int g = 8192 + t; wl[(g / 131) * 133 + g % 131] = tct; }
        if (t < 256) d2row[t] = td;
        T2l[t] = tt0;
        T2l[512 + t] = tt1;
        if (t < 128) T2l[1024 + t] = tt2;
        if (t < 234) mom[t] = tmo;
        if (t < 3) x0l[t] = tx;
    }
    __syncthreads();
    {
        int q = t >> 7, v = t & 127;
        const float* Wt = ws + OFF_WF1T + (q * 64) * 128 + v;
        const float* d = d2row + q * 64;
        float s = 0.f;
#pragma unroll 8
        for (int e = 0; e < 64; ++e) s = fmaf(d[e], Wt[e * 128], s);
        zp[q * 128 + v] = s;
    }
    __syncthreads();
    if (t < 128)
        zl[t] = bf1[t] + ((zp[t] + zp[128 + t]) + (zp[256 + t] + zp[384 + t]));
    __syncthreads();
    if (t < 384) {
        const float* Vt = ws + OFF_V;
        float s0 = 0.f;
#pragma unroll 8
        for (int v = 0; v < 128; ++v) s0 = fmaf(zl[v], Vt[v * 384 + t], s0);
        U2l[t] = s0;
        ws[OFF_U2 + b * 384 + t] = s0;
    } else if (t < 448) {
        int m = t - 384;
        const float* w = wl + m * 133;
        float s = bcm[m];
#pragma unroll 4
        for (int i = 0; i < 128; ++i) s = fmaf(zl[i], w[i], s);
        s = fmaf(x0l[0], w[128], s);
        s = fmaf(x0l[1], w[129], s);
        s = fmaf(x0l[2], w[130], s);
        ws[OFF_C2 + b * 64 + m] = s;
        C2l[m] = s;
    }
    __syncthreads();
    if (t < 64) {
        int m = t;
        float T[18], U[6];
#pragma unroll
        for (int r = 0; r < 18; ++r) T[r] = T2l[m * 18 + r];
#pragma unroll
        for (int a = 0; a < 6; ++a) U[a] = U2l[m * 6 + a];
        float S = 0.f;
#pragma unroll
        for (int a = 0; a < 6; ++a) {
            S = fmaf(mom[6 + a * 3 + 0], T[a * 3 + 0], S);
            S = fmaf(mom[6 + a * 3 + 1], T[a * 3 + 1], S);
            S = fmaf(mom[6 + a * 3 + 2], T[a * 3 + 2], S);
            S = fmaf(mom[a], U[a], S);
        }
        float qd = 0.f, qo = 0.f;
#pragma unroll
        for (int a = 0; a < 6; ++a)
#pragma unroll
            for (int a2 = a; a2 < 6; ++a2) {
                int p = a * 6 - (a * (a - 1)) / 2 + (a2 - a);
                const float* b3 = mom + 108 + p * 6;   // (00,01,02,11,12,22)
                const float* b2m = mom + 45 + p * 3;
                float b1v = mom[24 + p];
                float Ta0 = T[a * 3], Ta1 = T[a * 3 + 1], Ta2 = T[a * 3 + 2];
                float Tb0 = T[a2 * 3], Tb1 = T[a2 * 3 + 1], Tb2 = T[a2 * 3 + 2];
                float w0 = b3[0] * Ta0 + b3[1] * Ta1 + b3[2] * Ta2;
                float w1 = b3[1] * Ta0 + b3[3] * Ta1 + b3[4] * Ta2;
                float w2 = b3[2] * Ta0 + b3[4] * Ta1 + b3[5] * Ta2;
                float term = w0 * Tb0 + w1 * Tb1 + w2 * Tb2;
                float d1 = b2m[0] * Ta0 + b2m[1] * Ta1 + b2m[2] * Ta2;
                float d2_ = b2m[0] * Tb0 + b2m[1] * Tb1 + b2m[2] * Tb2;
                term += U[a2] * d1 + U[a] * d2_ + U[a] * U[a2] * b1v;
                if (a == a2) qd += term; else qo += term;
            }
        float Q = qd + 2.f * qo;
        float xx0 = x0l[0], xx1 = x0l[1], xx2 = x0l[2];
        float rn = xx0 * xx0 + xx1 * xx1 + xx2 * xx2;
        float inv = 1.f / (sqrtf(rn) + 1e-8f);
        float c2[6];
        c2[0] = fmaxf(xx2, 0.f) * inv; c2[1] = fmaxf(-xx2, 0.f) * inv;
        c2[2] = fmaxf(xx1, 0.f) * inv; c2[3] = fmaxf(-xx1, 0.f) * inv;
        c2[4] = fmaxf(xx0, 0.f) * inv; c2[5] = fmaxf(-xx0, 0.f) * inv;
        float h0 = 0.f;
#pragma unroll
        for (int a = 0; a < 6; ++a) {
            float cc = c2[a] * c2[a];
            float ta = fmaf(xx0, T[a * 3], fmaf(xx1, T[a * 3 + 1], fmaf(xx2, T[a * 3 + 2], U[a])));
            h0 = fmaf(cc, ta, h0);
        }
        float C2v = C2l[m];
        S += C2v - h0;
        Q += C2v * C2v - h0 * h0;
        atomicAdd(&ws[OFF_GP2 + m], S);
        atomicAdd(&ws[OFF_GP2 + 64 + m], Q);
    }
}

// ---------------------------------------------------------------------------
// k_e: epilogue; per-block bn3 scale/off from the single GP2 row (identical
// FP order in every block -> deterministic).
__global__ __launch_bounds__(512) void k_e(const float* __restrict__ x,
                                           const float* __restrict__ g3,
                                           const float* __restrict__ b3,
                                           const float* __restrict__ Wf2,
                                           const float* __restrict__ bf2,
                                           const float* __restrict__ ws,
                                           float* __restrict__ out) {
    __shared__ __attribute__((aligned(16))) float L[6464];
    float* Wl24 = L;           // [64][24]: {T2 at a*4+j, U2 at a*4+3}
    float* Pl   = L + 1536;    // [64][12]: {Wf2[0..6], scale@7, off@8}
    float* C2l  = L + 2304;    // [64]
    float* yp   = L + 2368;    // [256][16]
    int blk = blockIdx.x, t = threadIdx.x;
    int b = blk >> 3;
    for (int g = t; g < 1152; g += 512) {
        int m = g / 18, r = g % 18, a = r / 3, j = r % 3;
        Wl24[m * 24 + a * 4 + j] = ws[OFF_T2 + g];
    }
    if (t < 384)
        Wl24[(t / 6) * 24 + (t % 6) * 4 + 3] = ws[OFF_U2 + b * 384 + t];
    if (t < 448) {
        int m = t / 7, k = t % 7;
        Pl[m * 12 + k] = Wf2[k * 64 + m];
    }
    if (t < 64) {
        float S = ws[OFF_GP2 + t];
        float Q = ws[OFF_GP2 + 64 + t];
        float mean = S * (1.f / 131072.f);
        float var = Q * (1.f / 131072.f) - mean * mean;
        float scale = g3[t] * rsqrtf(var + 1e-5f);
        Pl[t * 12 + 7] = scale;
        Pl[t * 12 + 8] = b3[t] - mean * scale;
    }
    if ((blk & 7) == 0 && t < 64) C2l[t] = ws[OFF_C2 + b * 64 + t];
    __syncthreads();

    int p_loc = t >> 1, mh = t & 1;
    int p = blk * 256 + p_loc;
    const float* xp = x + (size_t)p * 10;
    float x0 = xp[0], x1 = xp[1], x2 = xp[2];
    float rn = x0 * x0 + x1 * x1 + x2 * x2;
    float inv = 1.f / (sqrtf(rn) + 1e-8f);
    float c2[6];
    c2[0] = fmaxf(x2, 0.f) * inv; c2[1] = fmaxf(-x2, 0.f) * inv;
    c2[2] = fmaxf(x1, 0.f) * inv; c2[3] = fmaxf(-x1, 0.f) * inv;
    c2[4] = fmaxf(x0, 0.f) * inv; c2[5] = fmaxf(-x0, 0.f) * inv;
#pragma unroll
    for (int a = 0; a < 6; ++a) c2[a] *= c2[a];
    bool c0 = ((p & 2047) == 0);
    float y[7];
#pragma unroll
    for (int k = 0; k < 7; ++k) y[k] = mh ? 0.f : bf2[k];
    int m0 = mh * 32;
#pragma unroll 4
    for (int mm = 0; mm < 32; ++mm) {
        int m = m0 + mm;
        const float4* Wm = (const float4*)(Wl24 + m * 24);
        float h = 0.f;
#pragma unroll
        for (int a = 0; a < 6; ++a) {
            float4 wq = Wm[a];   // {T0,T1,T2,U}
            float ta = fmaf(x0, wq.x, fmaf(x1, wq.y, fmaf(x2, wq.z, wq.w)));
            h = fmaf(c2[a], ta, h);
        }
        if (c0) h = C2l[m];
        const float4* Pm = (const float4*)(Pl + m * 12);
        float4 p0 = Pm[0], p1 = Pm[1];
        float offv = Pl[m * 12 + 8];
        float r = fmaxf(fmaf(h, p1.w, offv), 0.f);
        y[0] = fmaf(r, p0.x, y[0]); y[1] = fmaf(r, p0.y, y[1]);
        y[2] = fmaf(r, p0.z, y[2]); y[3] = fmaf(r, p0.w, y[3]);
        y[4] = fmaf(r, p1.x, y[4]); y[5] = fmaf(r, p1.y, y[5]);
        y[6] = fmaf(r, p1.z, y[6]);
    }
#pragma unroll
    for (int k = 0; k < 7; ++k) yp[p_loc * 16 + mh * 8 + k] = y[k];
    __syncthreads();
    float* op = out + (size_t)blk * 1792;
    for (int g = t; g < 1792; g += 512) {
        int pp = g / 7, k = g % 7;
        float v = yp[pp * 16 + k] + yp[pp * 16 + 8 + k];
        op[g] = 1.f / (1.f + __expf(-v));
    }
}

// ---------------------------------------------------------------------------
extern "C" void kernel_launch(void* const* d_in, const int* in_sizes, int n_in,
                              void* d_out, int out_size, void* d_ws, size_t ws_size,
                              hipStream_t stream) {
    const float* x     = (const float*)d_in[0];
    // d_in[1]=Wc, d_in[2]=bc : dead code in reference
    const float* Wdir  = (const float*)d_in[3];
    const float* g1    = (const float*)d_in[4];
    const float* b1    = (const float*)d_in[5];
    const float* Wdir2 = (const float*)d_in[6];
    const float* g2    = (const float*)d_in[7];
    const float* b2    = (const float*)d_in[8];
    const float* Wf1   = (const float*)d_in[9];
    const float* bf1   = (const float*)d_in[10];
    const float* Wcm   = (const float*)d_in[11];
    const float* bcm   = (const float*)d_in[12];
    const float* Wdc   = (const float*)d_in[13];
    const float* Wm0   = (const float*)d_in[14];
    const float* g3    = (const float*)d_in[15];
    const float* b3    = (const float*)d_in[16];
    const float* Wf2   = (const float*)d_in[17];
    const float* bf2   = (const float*)d_in[18];
    float* ws  = (float*)d_ws;
    float* out = (float*)d_out;

    k_wa <<<243, 256, 0, stream>>>(x, Wm0, Wdc, Wf1, ws);
    k_d2 <<<64,  256, 0, stream>>>(Wdir, g1, b1, Wdir2, g2, b2, ws);
    k_z  <<<64,  512, 0, stream>>>(x, bf1, Wcm, bcm, ws);
    k_e  <<<512, 512, 0, stream>>>(x, g3, b3, Wf2, bf2, ws, out);
}

// Round 13
// 148.387 us; speedup vs baseline: 1.3434x; 1.0020x over previous
//
#include <hip/hip_runtime.h>
#include <math.h>

// Problem constants
#define BATCH 64
#define NPTS  2048
// ws float offsets
#define OFF_M    0       // [64][61] M[b][c*6+a], Sdw at [b][60] (dead after k_d2)
#define OFF_T2   4096    // [64][18]  T2[m][a*3+j]
#define OFF_GP2  5248    // [128] S[64], Q[64] (atomic, zeroed by k_wa)
#define OFF_V    8192    // TRANSPOSED: Vt[v][ma] = [128][384]
#define OFF_WF1T 57344   // Wf1 transposed: [256 e][128 v]
#define OFF_D2P  90112   // [64][256] relu(bn2(d2))
#define OFF_C2   114688  // [64][64]  center2[b][m] (written by k_z)
#define OFF_U2   118784  // [64][384] U2[b][ma] (written by k_z)
#define OFF_MOM  143360  // [64][240] per-batch moments: A1[6],A2[18],B1[21],B2[63],B3[126]

// ---------------------------------------------------------------------------
// k_wa: blocks 0..23    fold-V as tiled GEMM (a, v-quarter), SW-pipelined
//       blocks 24..41   fold-T2 (one (a,j) pair per block)
//       blocks 42..105  stage-A per-batch moments (M, dw-weighted)
//       block 106       zero GP2
//       blocks 107..114 transpose Wf1 -> Wf1t
//       blocks 115..178 bn3 moments group0: B3
//       blocks 179..242 bn3 moments group1: A1,A2,B1,B2
__global__ __launch_bounds__(256) void k_wa(const float* __restrict__ x,
                                            const float* __restrict__ Wm0,
                                            const float* __restrict__ Wdc,
                                            const float* __restrict__ Wf1,
                                            float* __restrict__ ws) {
    __shared__ __attribute__((aligned(16))) float L[61 * 257];
    int blk = blockIdx.x, t = threadIdx.x;
    if (blk < 24) {
        // fold V, software-pipelined: reg-load tile k+1 while computing tile k
        float* wml = L;            // [64][33]
        float* pl  = L + 2112;     // [32][36]
        int a = blk >> 2, vq = blk & 3;
        int m = t & 63, vg = t >> 6;
        float acc[8];
#pragma unroll
        for (int i = 0; i < 8; ++i) acc[i] = 0.f;
        float rm[8], rp[4];
#pragma unroll
        for (int i = 0; i < 8; ++i) {
            int g = t + 256 * i;
            rm[i] = Wm0[(g >> 5) * 256 + (g & 31)];
        }
#pragma unroll
        for (int i = 0; i < 4; ++i) {
            int g = t + 256 * i;
            rp[i] = Wdc[((g >> 5) * 6 + a) * 131 + 3 + vq * 32 + (g & 31)];
        }
        for (int tile = 0; tile < 8; ++tile) {
#pragma unroll
            for (int i = 0; i < 8; ++i) {
                int g = t + 256 * i;
                wml[(g >> 5) * 33 + (g & 31)] = rm[i];
            }
#pragma unroll
            for (int i = 0; i < 4; ++i) {
                int g = t + 256 * i;
                pl[(g >> 5) * 36 + (g & 31)] = rp[i];
            }
            __syncthreads();
            if (tile < 7) {
                int e1 = (tile + 1) * 32;
#pragma unroll
                for (int i = 0; i < 8; ++i) {
                    int g = t + 256 * i;
                    rm[i] = Wm0[(g >> 5) * 256 + e1 + (g & 31)];
                }
#pragma unroll
                for (int i = 0; i < 4; ++i) {
                    int g = t + 256 * i;
                    rp[i] = Wdc[((e1 + (g >> 5)) * 6 + a) * 131 + 3 + vq * 32 + (g & 31)];
                }
            }
#pragma unroll
            for (int e = 0; e < 32; ++e) {
                float wv = wml[m * 33 + e];
                const float4* p4 = (const float4*)(pl + e * 36 + vg * 8);
                float4 pa = p4[0], pb = p4[1];
                acc[0] = fmaf(wv, pa.x, acc[0]); acc[1] = fmaf(wv, pa.y, acc[1]);
                acc[2] = fmaf(wv, pa.z, acc[2]); acc[3] = fmaf(wv, pa.w, acc[3]);
                acc[4] = fmaf(wv, pb.x, acc[4]); acc[5] = fmaf(wv, pb.y, acc[5]);
                acc[6] = fmaf(wv, pb.z, acc[6]); acc[7] = fmaf(wv, pb.w, acc[7]);
            }
            __syncthreads();
        }
#pragma unroll
        for (int vv = 0; vv < 8; ++vv)
            ws[OFF_V + (vq * 32 + vg * 8 + vv) * 384 + m * 6 + a] = acc[vv];
    } else if (blk < 42) {
        float* col = L;
        float* red = L + 256;
        int p = blk - 24, a = p / 3, j = p % 3;
        col[t] = Wdc[(t * 6 + a) * 131 + j];
        __syncthreads();
        int m = t >> 2, q = t & 3;
        const float* wm = Wm0 + m * 256 + q * 64;
        const float* cl = col + q * 64;
        float s = 0.f;
#pragma unroll 16
        for (int i = 0; i < 64; ++i) s = fmaf(wm[i], cl[i], s);
        red[t] = s;
        __syncthreads();
        if (t < 64) {
            float v = (red[t * 4] + red[t * 4 + 1]) + (red[t * 4 + 2] + red[t * 4 + 3]);
            ws[OFF_T2 + t * 18 + a * 3 + j] = v;
        }
    } else if (blk < 106) {
        int b = blk - 42;
        float* red = L;                        // [61][257]
        float acc[61];
#pragma unroll
        for (int i = 0; i < 61; ++i) acc[i] = 0.f;
#pragma unroll 2
        for (int k = 0; k < 8; ++k) {
            int n = t + 256 * k;
            const float* xp = x + (size_t)(b * NPTS + n) * 10;
            float xv[10];
#pragma unroll
            for (int j = 0; j < 5; ++j) {
                float2 v = *(const float2*)(xp + 2 * j);
                xv[2 * j] = v.x; xv[2 * j + 1] = v.y;
            }
            float x0 = xv[0], x1 = xv[1], x2 = xv[2];
            float rn = x0 * x0 + x1 * x1 + x2 * x2;
            float norm = sqrtf(rn);
            float inv = 1.f / (norm + 1e-8f);
            float c2[6];
            c2[0] = fmaxf(x2, 0.f) * inv; c2[1] = fmaxf(-x2, 0.f) * inv;
            c2[2] = fmaxf(x1, 0.f) * inv; c2[3] = fmaxf(-x1, 0.f) * inv;
            c2[4] = fmaxf(x0, 0.f) * inv; c2[5] = fmaxf(-x0, 0.f) * inv;
#pragma unroll
            for (int a = 0; a < 6; ++a) c2[a] *= c2[a];
            float dw = 1.f - (rn - 1.f) * (1.f / 3.f);
            if (dw < 0.f) dw = 0.f;
            if (norm <= 0.f) dw = 0.f;
            float cw[6];
#pragma unroll
            for (int a = 0; a < 6; ++a) cw[a] = c2[a] * dw;
#pragma unroll
            for (int c = 0; c < 10; ++c) {
                float dv = (c < 7) ? xv[3 + c] : xv[c - 7];
#pragma unroll
                for (int a = 0; a < 6; ++a)
                    acc[c * 6 + a] = fmaf(dv, cw[a], acc[c * 6 + a]);
            }
            acc[60] += dw;
        }
#pragma unroll
        for (int i = 0; i < 61; ++i) red[i * 257 + t] = acc[i];
        __syncthreads();
        if (t < 61) {
            float s = 0.f;
#pragma unroll 8
            for (int j = 0; j < 256; ++j) s += red[t * 257 + j];
            ws[OFF_M + b * 61 + t] = s;
        }
    } else if (blk == 106) {
        if (t < 128) ws[OFF_GP2 + t] = 0.f;
    } else if (blk < 115) {
        float* slab = L;                       // [16][257]
        int w = blk - 107, v0 = w * 16;
        for (int g = t; g < 4096; g += 256)
            slab[(g >> 8) * 257 + (g & 255)] = Wf1[(v0 + (g >> 8)) * 256 + (g & 255)];
        __syncthreads();
        for (int g = t; g < 4096; g += 256) {
            int e = g >> 4, vl = g & 15;
            ws[OFF_WF1T + e * 128 + v0 + vl] = slab[vl * 257 + e];
        }
    } else if (blk < 179) {
        int b = blk - 115;
        float* red = L;
        float acc[126];
#pragma unroll
        for (int i = 0; i < 126; ++i) acc[i] = 0.f;
#pragma unroll 2
        for (int k = 0; k < 8; ++k) {
            int n = t + 256 * k;
            const float* xp = x + (size_t)(b * NPTS + n) * 10;
            float2 v01 = *(const float2*)xp;
            float x0 = v01.x, x1 = v01.y, x2 = xp[2];
            float rn = x0 * x0 + x1 * x1 + x2 * x2;
            float inv = 1.f / (sqrtf(rn) + 1e-8f);
            float c[6];
            c[0] = fmaxf(x2, 0.f) * inv; c[1] = fmaxf(-x2, 0.f) * inv;
            c[2] = fmaxf(x1, 0.f) * inv; c[3] = fmaxf(-x1, 0.f) * inv;
            c[4] = fmaxf(x0, 0.f) * inv; c[5] = fmaxf(-x0, 0.f) * inv;
#pragma unroll
            for (int a = 0; a < 6; ++a) c[a] *= c[a];
            float xx[6] = {x0 * x0, x0 * x1, x0 * x2, x1 * x1, x1 * x2, x2 * x2};
#pragma unroll
            for (int a = 0; a < 6; ++a)
#pragma unroll
                for (int a2 = a; a2 < 6; ++a2) {
                    int p = a * 6 - (a * (a - 1)) / 2 + (a2 - a);
                    float cc = c[a] * c[a2];
#pragma unroll
                    for (int q = 0; q < 6; ++q)
                        acc[p * 6 + q] = fmaf(cc, xx[q], acc[p * 6 + q]);
                }
        }
#pragma unroll
        for (int i = 0; i < 61; ++i) red[i * 257 + t] = acc[i];
        __syncthreads();
        if (t < 61) {
            float s = 0.f;
#pragma unroll 8
            for (int j = 0; j < 256; ++j) s += red[t * 257 + j];
            ws[OFF_MOM + b * 240 + 108 + t] = s;
        }
        __syncthreads();
#pragma unroll
        for (int i = 0; i < 61; ++i) red[i * 257 + t] = acc[61 + i];
        __syncthreads();
        if (t < 61) {
            float s = 0.f;
#pragma unroll 8
            for (int j = 0; j < 256; ++j) s += red[t * 257 + j];
            ws[OFF_MOM + b * 240 + 108 + 61 + t] = s;
        }
        __syncthreads();
#pragma unroll
        for (int i = 0; i < 4; ++i) red[i * 257 + t] = acc[122 + i];
        __syncthreads();
        if (t < 4) {
            float s = 0.f;
#pragma unroll 8
            for (int j = 0; j < 256; ++j) s += red[t * 257 + j];
            ws[OFF_MOM + b * 240 + 108 + 122 + t] = s;
        }
    } else {
        int b = blk - 179;
        float* red = L;
        float acc[108];
#pragma unroll
        for (int i = 0; i < 108; ++i) acc[i] = 0.f;
#pragma unroll 2
        for (int k = 0; k < 8; ++k) {
            int n = t + 256 * k;
            const float* xp = x + (size_t)(b * NPTS + n) * 10;
            float2 v01 = *(const float2*)xp;
            float x0 = v01.x, x1 = v01.y, x2 = xp[2];
            float rn = x0 * x0 + x1 * x1 + x2 * x2;
            float inv = 1.f / (sqrtf(rn) + 1e-8f);
            float c[6];
            c[0] = fmaxf(x2, 0.f) * inv; c[1] = fmaxf(-x2, 0.f) * inv;
            c[2] = fmaxf(x1, 0.f) * inv; c[3] = fmaxf(-x1, 0.f) * inv;
            c[4] = fmaxf(x0, 0.f) * inv; c[5] = fmaxf(-x0, 0.f) * inv;
#pragma unroll
            for (int a = 0; a < 6; ++a) c[a] *= c[a];
#pragma unroll
            for (int a = 0; a < 6; ++a) {
                acc[a] += c[a];
                acc[6 + a * 3 + 0] = fmaf(c[a], x0, acc[6 + a * 3 + 0]);
                acc[6 + a * 3 + 1] = fmaf(c[a], x1, acc[6 + a * 3 + 1]);
                acc[6 + a * 3 + 2] = fmaf(c[a], x2, acc[6 + a * 3 + 2]);
            }
#pragma unroll
            for (int a = 0; a < 6; ++a)
#pragma unroll
                for (int a2 = a; a2 < 6; ++a2) {
                    int p = a * 6 - (a * (a - 1)) / 2 + (a2 - a);
                    float cc = c[a] * c[a2];
                    acc[24 + p] += cc;
                    acc[45 + p * 3 + 0] = fmaf(cc, x0, acc[45 + p * 3 + 0]);
                    acc[45 + p * 3 + 1] = fmaf(cc, x1, acc[45 + p * 3 + 1]);
                    acc[45 + p * 3 + 2] = fmaf(cc, x2, acc[45 + p * 3 + 2]);
                }
        }
#pragma unroll
        for (int i = 0; i < 61; ++i) red[i * 257 + t] = acc[i];
        __syncthreads();
        if (t < 61) {
            float s = 0.f;
#pragma unroll 8
            for (int j = 0; j < 256; ++j) s += red[t * 257 + j];
            ws[OFF_MOM + b * 240 + t] = s;
        }
        __syncthreads();
#pragma unroll
        for (int i = 0; i < 47; ++i) red[i * 257 + t] = acc[61 + i];
        __syncthreads();
        if (t < 47) {
            float s = 0.f;
#pragma unroll 8
            for (int j = 0; j < 256; ++j) s += red[t * 257 + j];
            ws[OFF_MOM + b * 240 + 61 + t] = s;
        }
    }
}

// ---------------------------------------------------------------------------
// k_d2: 64 blocks; h1/bn1 redundant + d2/bn2 for 4 owned e-columns.
// Staging register-batched (proven round 11).
__global__ __launch_bounds__(256) void k_d2(const float* __restrict__ Wdir,
                                            const float* __restrict__ g1,
                                            const float* __restrict__ b1,
                                            const float* __restrict__ Wdir2,
                                            const float* __restrict__ g2,
                                            const float* __restrict__ b2,
                                            float* __restrict__ ws) {
    __shared__ float L[12704];
    float* Wd  = L;            // [64][61]
    float* Ml  = L + 3904;     // [64][61]
    float* h1  = L + 7808;     // [64][65]
    float* wt2 = L + 11968;    // [4][65]
    float* d2l = L + 12228;    // [64][5]
    float* sc  = L + 12548;    // [64]
    float* of  = L + 12612;    // [64]
    float* scl = L + 12676;    // [4]
    float* ofl = L + 12680;    // [4]
    int blk = blockIdx.x, t = threadIdx.x;
    int e_base = blk * 4;
    {
        float tm[15], tw[15];
#pragma unroll
        for (int i = 0; i < 15; ++i) tm[i] = ws[OFF_M + t + i * 256];
        float tmt = (t < 64) ? ws[OFF_M + 3840 + t] : 0.f;
#pragma unroll
        for (int i = 0; i < 15; ++i) tw[i] = Wdir[t + i * 256];
        float w2v = Wdir2[(e_base + (t >> 6)) * 64 + (t & 63)];
#pragma unroll
        for (int i = 0; i < 15; ++i) Ml[t + i * 256] = tm[i];
        if (t < 64) Ml[3840 + t] = tmt;
#pragma unroll
        for (int i = 0; i < 15; ++i) {
            int g = t + i * 256;
            Wd[(g / 60) * 61 + g % 60] = tw[i];
        }
        wt2[(t >> 6) * 65 + (t & 63)] = w2v;
    }
    __syncthreads();
    int m = t & 63;
    float Wr[60];
#pragma unroll
    for (int r = 0; r < 60; ++r) Wr[r] = Wd[m * 61 + r];
#pragma unroll
    for (int k = 0; k < 16; ++k) {
        int idx = t + 256 * k;
        int b = idx >> 6;
        const float* Mb = Ml + b * 61;
        float s = 0.f;
#pragma unroll
        for (int a = 0; a < 6; ++a)
#pragma unroll
            for (int c = 0; c < 10; ++c)
                s = fmaf(Wr[a * 10 + c], Mb[c * 6 + a], s);
        h1[b * 65 + m] = s / Mb[60];
    }
    __syncthreads();
    if (t < 64) {
        float s = 0.f, q = 0.f;
#pragma unroll 8
        for (int b = 0; b < 64; ++b) { float v = h1[b * 65 + t]; s += v; q = fmaf(v, v, q); }
        float mean = s * (1.f / 64.f);
        float var = q * (1.f / 64.f) - mean * mean;
        float scale = g1[t] * rsqrtf(var + 1e-5f);
        sc[t] = scale; of[t] = b1[t] - mean * scale;
    }
    __syncthreads();
#pragma unroll
    for (int k = 0; k < 16; ++k) {
        int idx = t + 256 * k;
        int b = idx >> 6;
        h1[b * 65 + m] = fmaxf(fmaf(h1[b * 65 + m], sc[m], of[m]), 0.f);
    }
    __syncthreads();
    {
        int b = t >> 2, el = t & 3;
        const float* h = h1 + b * 65;
        const float* w = wt2 + el * 65;
        float s = 0.f;
#pragma unroll
        for (int mm = 0; mm < 64; ++mm) s = fmaf(h[mm], w[mm], s);
        d2l[b * 5 + el] = s;
    }
    __syncthreads();
    if (t < 4) {
        float s = 0.f, q = 0.f;
#pragma unroll 8
        for (int b = 0; b < 64; ++b) { float v = d2l[b * 5 + t]; s += v; q = fmaf(v, v, q); }
        float mean = s * (1.f / 64.f);
        float var = q * (1.f / 64.f) - mean * mean;
        int E = e_base + t;
        float scale = g2[E] * rsqrtf(var + 1e-5f);
        scl[t] = scale; ofl[t] = b2[E] - mean * scale;
    }
    __syncthreads();
    {
        int b = t >> 2, el = t & 3;
        float v = fmaxf(fmaf(d2l[b * 5 + el], scl[el], ofl[el]), 0.f);
        ws[OFF_D2P + b * 256 + e_base + el] = v;
    }
}

// ---------------------------------------------------------------------------
// k_z: one block per batch: z, U2, C2, closed-form bn3 S/Q + point-0
// correction -> GP2. Staging register-batched; big scans unroll-16 for MLP.
__global__ __launch_bounds__(512) void k_z(const float* __restrict__ x,
                                           const float* __restrict__ bf1,
                                           const float* __restrict__ Wcm,
                                           const float* __restrict__ bcm,
                                           float* __restrict__ ws) {
    __shared__ float L[11252];
    float* d2row = L;          // [256]
    float* T2l   = L + 256;    // [1152]
    float* zp    = L + 1408;   // [4][128]
    float* zl    = L + 1920;   // [128]
    float* U2l   = L + 2048;   // [384]
    float* C2l   = L + 2432;   // [64]
    float* mom   = L + 2496;   // [240]
    float* x0l   = L + 2736;   // [4]
    float* wl    = L + 2740;   // [64][133] Wcm padded
    int b = blockIdx.x, t = threadIdx.x;
    {
        float tc[16];
#pragma unroll
        for (int i = 0; i < 16; ++i) tc[i] = Wcm[t + i * 512];
        float tct = (t < 192) ? Wcm[8192 + t] : 0.f;
        float td  = (t < 256) ? ws[OFF_D2P + b * 256 + t] : 0.f;
        float tt0 = ws[OFF_T2 + t];
        float tt1 = ws[OFF_T2 + 512 + t];
        float tt2 = (t < 128) ? ws[OFF_T2 + 1024 + t] : 0.f;
        float tmo = (t < 234) ? ws[OFF_MOM + b * 240 + t] : 0.f;
        float tx  = (t < 3) ? x[(size_t)b * NPTS * 10 + t] : 0.f;
#pragma unroll
        for (int i = 0; i < 16; ++i) {
            int g = t + i * 512;
            wl[(g / 131) * 133 + g % 131] = tc[i];
        }
        if (t < 192) { int g = 8192 + t; wl[(g / 131) * 133 + g % 131] = tct; }
        if (t < 256) d2row[t] = td;
        T2l[t] = tt0;
        T2l[512 + t] = tt1;
        if (t < 128) T2l[1024 + t] = tt2;
        if (t < 234) mom[t] = tmo;
        if (t < 3) x0l[t] = tx;
    }
    __syncthreads();
    {
        int q = t >> 7, v = t & 127;
        const float* Wt = ws + OFF_WF1T + (q * 64) * 128 + v;
        const float* d = d2row + q * 64;
        float s = 0.f;
#pragma unroll 16
        for (int e = 0; e < 64; ++e) s = fmaf(d[e], Wt[e * 128], s);
        zp[q * 128 + v] = s;
    }
    __syncthreads();
    if (t < 128)
        zl[t] = bf1[t] + ((zp[t] + zp[128 + t]) + (zp[256 + t] + zp[384 + t]));
    __syncthreads();
    if (t < 384) {
        const float* Vt = ws + OFF_V;
        float s0 = 0.f;
#pragma unroll 16
        for (int v = 0; v < 128; ++v) s0 = fmaf(zl[v], Vt[v * 384 + t], s0);
        U2l[t] = s0;
        ws[OFF_U2 + b * 384 + t] = s0;
    } else if (t < 448) {
        int m = t - 384;
        const float* w = wl + m * 133;
        float s = bcm[m];
#pragma unroll 4
        for (int i = 0; i < 128; ++i) s = fmaf(zl[i], w[i], s);
        s = fmaf(x0l[0], w[128], s);
        s = fmaf(x0l[1], w[129], s);
        s = fmaf(x0l[2], w[130], s);
        ws[OFF_C2 + b * 64 + m] = s;
        C2l[m] = s;
    }
    __syncthreads();
    if (t < 64) {
        int m = t;
        float T[18], U[6];
#pragma unroll
        for (int r = 0; r < 18; ++r) T[r] = T2l[m * 18 + r];
#pragma unroll
        for (int a = 0; a < 6; ++a) U[a] = U2l[m * 6 + a];
        float S = 0.f;
#pragma unroll
        for (int a = 0; a < 6; ++a) {
            S = fmaf(mom[6 + a * 3 + 0], T[a * 3 + 0], S);
            S = fmaf(mom[6 + a * 3 + 1], T[a * 3 + 1], S);
            S = fmaf(mom[6 + a * 3 + 2], T[a * 3 + 2], S);
            S = fmaf(mom[a], U[a], S);
        }
        float qd = 0.f, qo = 0.f;
#pragma unroll
        for (int a = 0; a < 6; ++a)
#pragma unroll
            for (int a2 = a; a2 < 6; ++a2) {
                int p = a * 6 - (a * (a - 1)) / 2 + (a2 - a);
                const float* b3 = mom + 108 + p * 6;   // (00,01,02,11,12,22)
                const float* b2m = mom + 45 + p * 3;
                float b1v = mom[24 + p];
                float Ta0 = T[a * 3], Ta1 = T[a * 3 + 1], Ta2 = T[a * 3 + 2];
                float Tb0 = T[a2 * 3], Tb1 = T[a2 * 3 + 1], Tb2 = T[a2 * 3 + 2];
                float w0 = b3[0] * Ta0 + b3[1] * Ta1 + b3[2] * Ta2;
                float w1 = b3[1] * Ta0 + b3[3] * Ta1 + b3[4] * Ta2;
                float w2 = b3[2] * Ta0 + b3[4] * Ta1 + b3[5] * Ta2;
                float term = w0 * Tb0 + w1 * Tb1 + w2 * Tb2;
                float d1 = b2m[0] * Ta0 + b2m[1] * Ta1 + b2m[2] * Ta2;
                float d2_ = b2m[0] * Tb0 + b2m[1] * Tb1 + b2m[2] * Tb2;
                term += U[a2] * d1 + U[a] * d2_ + U[a] * U[a2] * b1v;
                if (a == a2) qd += term; else qo += term;
            }
        float Q = qd + 2.f * qo;
        float xx0 = x0l[0], xx1 = x0l[1], xx2 = x0l[2];
        float rn = xx0 * xx0 + xx1 * xx1 + xx2 * xx2;
        float inv = 1.f / (sqrtf(rn) + 1e-8f);
        float c2[6];
        c2[0] = fmaxf(xx2, 0.f) * inv; c2[1] = fmaxf(-xx2, 0.f) * inv;
        c2[2] = fmaxf(xx1, 0.f) * inv; c2[3] = fmaxf(-xx1, 0.f) * inv;
        c2[4] = fmaxf(xx0, 0.f) * inv; c2[5] = fmaxf(-xx0, 0.f) * inv;
        float h0 = 0.f;
#pragma unroll
        for (int a = 0; a < 6; ++a) {
            float cc = c2[a] * c2[a];
            float ta = fmaf(xx0, T[a * 3], fmaf(xx1, T[a * 3 + 1], fmaf(xx2, T[a * 3 + 2], U[a])));
            h0 = fmaf(cc, ta, h0);
        }
        float C2v = C2l[m];
        S += C2v - h0;
        Q += C2v * C2v - h0 * h0;
        atomicAdd(&ws[OFF_GP2 + m], S);
        atomicAdd(&ws[OFF_GP2 + 64 + m], Q);
    }
}

// ---------------------------------------------------------------------------
// k_e: epilogue; staging register-batched (issue all loads, then write);
// per-block bn3 scale/off from the single GP2 row (deterministic).
__global__ __launch_bounds__(512) void k_e(const float* __restrict__ x,
                                           const float* __restrict__ g3,
                                           const float* __restrict__ b3,
                                           const float* __restrict__ Wf2,
                                           const float* __restrict__ bf2,
                                           const float* __restrict__ ws,
                                           float* __restrict__ out) {
    __shared__ __attribute__((aligned(16))) float L[6464];
    float* Wl24 = L;           // [64][24]: {T2 at a*4+j, U2 at a*4+3}
    float* Pl   = L + 1536;    // [64][12]: {Wf2[0..6], scale@7, off@8}
    float* C2l  = L + 2304;    // [64]
    float* yp   = L + 2368;    // [256][16]
    int blk = blockIdx.x, t = threadIdx.x;
    int b = blk >> 3;
    bool first = (blk & 7) == 0;
    {
        // batched staging: issue all loads before any LDS write
        float ta0 = ws[OFF_T2 + t];
        float ta1 = ws[OFF_T2 + 512 + t];
        float ta2 = (t < 128) ? ws[OFF_T2 + 1024 + t] : 0.f;
        float tu  = (t < 384) ? ws[OFF_U2 + b * 384 + t] : 0.f;
        float tw  = (t < 448) ? Wf2[(t % 7) * 64 + (t / 7)] : 0.f;
        float tS  = (t < 64) ? ws[OFF_GP2 + t] : 0.f;
        float tQ  = (t < 64) ? ws[OFF_GP2 + 64 + t] : 0.f;
        float tg  = (t < 64) ? g3[t] : 0.f;
        float tb  = (t < 64) ? b3[t] : 0.f;
        float tc2 = (first && t < 64) ? ws[OFF_C2 + b * 64 + t] : 0.f;
        {
            int g = t, m = g / 18, r = g % 18;
            Wl24[m * 24 + (r / 3) * 4 + r % 3] = ta0;
        }
        {
            int g = t + 512, m = g / 18, r = g % 18;
            Wl24[m * 24 + (r / 3) * 4 + r % 3] = ta1;
        }
        if (t < 128) {
            int g = t + 1024, m = g / 18, r = g % 18;
            Wl24[m * 24 + (r / 3) * 4 + r % 3] = ta2;
        }
        if (t < 384) Wl24[(t / 6) * 24 + (t % 6) * 4 + 3] = tu;
        if (t < 448) Pl[(t / 7) * 12 + (t % 7)] = tw;
        if (t < 64) {
            float mean = tS * (1.f / 131072.f);
            float var = tQ * (1.f / 131072.f) - mean * mean;
            float scale = tg * rsqrtf(var + 1e-5f);
            Pl[t * 12 + 7] = scale;
            Pl[t * 12 + 8] = tb - mean * scale;
        }
        if (first && t < 64) C2l[t] = tc2;
    }
    __syncthreads();

    int p_loc = t >> 1, mh = t & 1;
    int p = blk * 256 + p_loc;
    const float* xp = x + (size_t)p * 10;
    float x0 = xp[0], x1 = xp[1], x2 = xp[2];
    float rn = x0 * x0 + x1 * x1 + x2 * x2;
    float inv = 1.f / (sqrtf(rn) + 1e-8f);
    float c2[6];
    c2[0] = fmaxf(x2, 0.f) * inv; c2[1] = fmaxf(-x2, 0.f) * inv;
    c2[2] = fmaxf(x1, 0.f) * inv; c2[3] = fmaxf(-x1, 0.f) * inv;
    c2[4] = fmaxf(x0, 0.f) * inv; c2[5] = fmaxf(-x0, 0.f) * inv;
#pragma unroll
    for (int a = 0; a < 6; ++a) c2[a] *= c2[a];
    bool c0 = ((p & 2047) == 0);
    float y[7];
#pragma unroll
    for (int k = 0; k < 7; ++k) y[k] = mh ? 0.f : bf2[k];
    int m0 = mh * 32;
#pragma unroll 4
    for (int mm = 0; mm < 32; ++mm) {
        int m = m0 + mm;
        const float4* Wm = (const float4*)(Wl24 + m * 24);
        float h = 0.f;
#pragma unroll
        for (int a = 0; a < 6; ++a) {
            float4 wq = Wm[a];   // {T0,T1,T2,U}
            float ta = fmaf(x0, wq.x, fmaf(x1, wq.y, fmaf(x2, wq.z, wq.w)));
            h = fmaf(c2[a], ta, h);
        }
        if (c0) h = C2l[m];
        const float4* Pm = (const float4*)(Pl + m * 12);
        float4 p0 = Pm[0], p1 = Pm[1];
        float offv = Pl[m * 12 + 8];
        float r = fmaxf(fmaf(h, p1.w, offv), 0.f);
        y[0] = fmaf(r, p0.x, y[0]); y[1] = fmaf(r, p0.y, y[1]);
        y[2] = fmaf(r, p0.z, y[2]); y[3] = fmaf(r, p0.w, y[3]);
        y[4] = fmaf(r, p1.x, y[4]); y[5] = fmaf(r, p1.y, y[5]);
        y[6] = fmaf(r, p1.z, y[6]);
    }
#pragma unroll
    for (int k = 0; k < 7; ++k) yp[p_loc * 16 + mh * 8 + k] = y[k];
    __syncthreads();
    float* op = out + (size_t)blk * 1792;
    for (int g = t; g < 1792; g += 512) {
        int pp = g / 7, k = g % 7;
        float v = yp[pp * 16 + k] + yp[pp * 16 + 8 + k];
        op[g] = 1.f / (1.f + __expf(-v));
    }
}

// ---------------------------------------------------------------------------
extern "C" void kernel_launch(void* const* d_in, const int* in_sizes, int n_in,
                              void* d_out, int out_size, void* d_ws, size_t ws_size,
                              hipStream_t stream) {
    const float* x     = (const float*)d_in[0];
    // d_in[1]=Wc, d_in[2]=bc : dead code in reference
    const float* Wdir  = (const float*)d_in[3];
    const float* g1    = (const float*)d_in[4];
    const float* b1    = (const float*)d_in[5];
    const float* Wdir2 = (const float*)d_in[6];
    const float* g2    = (const float*)d_in[7];
    const float* b2    = (const float*)d_in[8];
    const float* Wf1   = (const float*)d_in[9];
    const float* bf1   = (const float*)d_in[10];
    const float* Wcm   = (const float*)d_in[11];
    const float* bcm   = (const float*)d_in[12];
    const float* Wdc   = (const float*)d_in[13];
    const float* Wm0   = (const float*)d_in[14];
    const float* g3    = (const float*)d_in[15];
    const float* b3    = (const float*)d_in[16];
    const float* Wf2   = (const float*)d_in[17];
    const float* bf2   = (const float*)d_in[18];
    float* ws  = (float*)d_ws;
    float* out = (float*)d_out;

    k_wa <<<243, 256, 0, stream>>>(x, Wm0, Wdc, Wf1, ws);
    k_d2 <<<64,  256, 0, stream>>>(Wdir, g1, b1, Wdir2, g2, b2, ws);
    k_z  <<<64,  512, 0, stream>>>(x, bf1, Wcm, bcm, ws);
    k_e  <<<512, 512, 0, stream>>>(x, g3, b3, Wf2, bf2, ws, out);
}